// Round 7
// baseline (341.064 us; speedup 1.0000x reference)
//
#include <hip/hip_runtime.h>
#include <stdint.h>

#define D_DIM 1024
#define H_DIM 512
#define NEXP  8
#define NP    10            // 8 routed + 2 shared expert passes

#define BM 128
#define BN 128              // widened tile (m93 move)
#define BK 64
#define LDK 72              // BK + 8 pad -> 144B row stride (16B aligned)

typedef __attribute__((ext_vector_type(8))) short short8;     // 8 bf16 MFMA operand
typedef __attribute__((ext_vector_type(4))) float floatx4;    // MFMA accumulator
typedef __attribute__((ext_vector_type(4))) unsigned int uint4v;
typedef __attribute__((ext_vector_type(4))) float float4v;

__device__ __forceinline__ float bf2f(unsigned short u) {
    union { float f; unsigned int i; } v; v.i = ((unsigned int)u) << 16; return v.f;
}
__device__ __forceinline__ unsigned short f2bf(float f) {
    union { float f; unsigned int i; } v; v.f = f;
    unsigned int r = v.i + 0x7FFFu + ((v.i >> 16) & 1u);   // RNE
    return (unsigned short)(r >> 16);
}

// bf16 atomic add via CAS (fallback path, bf16-out only)
__device__ void atomAddBf16(unsigned short* pp, float v) {
    unsigned int* w = (unsigned int*)((size_t)pp & ~(size_t)3);
    const bool hi = ((size_t)pp & 2) != 0;
    unsigned int old = *w, assumed;
    do {
        assumed = old;
        unsigned short cur = hi ? (unsigned short)(assumed >> 16)
                                : (unsigned short)(assumed & 0xFFFFu);
        unsigned short nv = f2bf(bf2f(cur) + v);
        unsigned int repl = hi ? ((assumed & 0x0000FFFFu) | ((unsigned)nv << 16))
                               : ((assumed & 0xFFFF0000u) | nv);
        old = atomicCAS(w, assumed, repl);
    } while (old != assumed);
}

// ---------------------------------------------------------------------------
__global__ void detect_kernel(const unsigned short* __restrict__ x, int* flag)
{
    __shared__ int bad;
    if (threadIdx.x == 0) bad = 0;
    __syncthreads();
    int b = 0;
    for (int i = threadIdx.x; i < 8192; i += 256) {
        int e = (x[i] >> 7) & 0xFF;
        if (e >= 0xA0) b = 1;
    }
    if (b) atomicOr(&bad, 1);
    __syncthreads();
    if (threadIdx.x == 0) *flag = bad;
}

// ---------------------------------------------------------------------------
// w1 + w3 transpose+convert in ONE launch: z 0..9 -> w1t, z 10..19 -> w3t.
// ---------------------------------------------------------------------------
__global__ __launch_bounds__(256) void transp13_kernel(
    const void* __restrict__ rw1, const void* __restrict__ rw3,
    const void* __restrict__ sw1, const void* __restrict__ sw3,
    unsigned short* __restrict__ w1t, unsigned short* __restrict__ w3t,
    const int* __restrict__ flag)
{
    const int isf32 = *flag;
    const int z = blockIdx.z;
    const int grp = z / 10, zz = z % 10;
    const void* src_ = grp == 0 ? (zz < 8 ? rw1 : sw1) : (zz < 8 ? rw3 : sw3);
    unsigned short* dstB = grp == 0 ? w1t : w3t;
    const size_t moff = (size_t)(zz < 8 ? zz : zz - 8) * D_DIM * H_DIM;
    const int nl = threadIdx.x & 63, j = threadIdx.x >> 6;
    const int n = blockIdx.y * 64 + nl;
    const int k0 = blockIdx.x * 32 + j * 8;

    unsigned short v[8];
    if (isf32) {
        const float* src = (const float*)src_ + moff;
#pragma unroll
        for (int j2 = 0; j2 < 8; j2++) v[j2] = f2bf(src[(size_t)(k0 + j2) * H_DIM + n]);
    } else {
        const unsigned short* src = (const unsigned short*)src_ + moff;
#pragma unroll
        for (int j2 = 0; j2 < 8; j2++) v[j2] = src[(size_t)(k0 + j2) * H_DIM + n];
    }
    uint4v w;
#pragma unroll
    for (int q = 0; q < 4; q++) w[q] = (unsigned)v[2 * q] | ((unsigned)v[2 * q + 1] << 16);
    *(uint4v*)(dstB + ((size_t)zz * H_DIM + n) * D_DIM + k0) = w;
}

// ---------------------------------------------------------------------------
// Generic transpose (used for w2): src [nmat][K][N] -> dst bf16 [nmat][N][K]
// ---------------------------------------------------------------------------
__global__ __launch_bounds__(256) void transp_kernel(
    const void* __restrict__ rsrc, const void* __restrict__ ssrc,
    unsigned short* __restrict__ dst, int K, int N, const int* __restrict__ flag)
{
    const int isf32 = *flag;
    const int z = blockIdx.z;
    const size_t moff = (size_t)(z < 8 ? z : z - 8) * K * N;
    const int nl = threadIdx.x & 63, j = threadIdx.x >> 6;
    const int n = blockIdx.y * 64 + nl;
    const int k0 = blockIdx.x * 32 + j * 8;

    unsigned short v[8];
    if (isf32) {
        const float* src = (const float*)(z < 8 ? rsrc : ssrc) + moff;
#pragma unroll
        for (int j2 = 0; j2 < 8; j2++) v[j2] = f2bf(src[(size_t)(k0 + j2) * N + n]);
    } else {
        const unsigned short* src = (const unsigned short*)(z < 8 ? rsrc : ssrc) + moff;
#pragma unroll
        for (int j2 = 0; j2 < 8; j2++) v[j2] = src[(size_t)(k0 + j2) * N + n];
    }
    uint4v w;
#pragma unroll
    for (int q = 0; q < 4; q++) w[q] = (unsigned)v[2 * q] | ((unsigned)v[2 * q + 1] << 16);
    *(uint4v*)(dst + ((size_t)z * N + n) * K + k0) = w;
}

// ---------------------------------------------------------------------------
// Router: one wave per token -> top-2 ids + gates; fp32 mode also emits bf16 xb.
// ---------------------------------------------------------------------------
__global__ __launch_bounds__(256, 4) void router_kernel(
    const void* __restrict__ xv_, const void* __restrict__ rwv_,
    const void* __restrict__ rbv_, const int* __restrict__ flag,
    int* __restrict__ topkE, float2* __restrict__ topkG,
    unsigned short* __restrict__ xb, int useXb, int T)
{
    const int isf32 = *flag;
    int gid  = blockIdx.x * blockDim.x + threadIdx.x;
    int t    = gid >> 6;
    int lane = threadIdx.x & 63;
    if (t >= T) return;

    float acc[NEXP];
#pragma unroll
    for (int e = 0; e < NEXP; e++) acc[e] = 0.f;

    if (isf32) {
        const float* xr = (const float*)xv_ + (size_t)t * D_DIM;
        const float* rw = (const float*)rwv_;
        unsigned short* xo = xb + (size_t)t * D_DIM;
#pragma unroll 4
        for (int i = 0; i < D_DIM / 64; i++) {
            int d = i * 64 + lane;
            float xv = xr[d];
            if (useXb) xo[d] = f2bf(xv);
            float4v wa = *(const float4v*)(rw + (size_t)d * NEXP);
            float4v wb = *(const float4v*)(rw + (size_t)d * NEXP + 4);
#pragma unroll
            for (int q = 0; q < 4; q++) { acc[q] += xv * wa[q]; acc[q + 4] += xv * wb[q]; }
        }
    } else {
        const unsigned short* xr = (const unsigned short*)xv_ + (size_t)t * D_DIM;
        const unsigned short* rw = (const unsigned short*)rwv_;
#pragma unroll 4
        for (int i = 0; i < D_DIM / 64; i++) {
            int d = i * 64 + lane;
            float xv = bf2f(xr[d]);
            uint4v wv = *(const uint4v*)(rw + (size_t)d * NEXP);
#pragma unroll
            for (int q = 0; q < 4; q++) {
                unsigned int w = wv[q];
                acc[q * 2 + 0] += xv * bf2f((unsigned short)(w & 0xFFFFu));
                acc[q * 2 + 1] += xv * bf2f((unsigned short)(w >> 16));
            }
        }
    }
#pragma unroll
    for (int m = 32; m >= 1; m >>= 1) {
#pragma unroll
        for (int e = 0; e < NEXP; e++) acc[e] += __shfl_xor(acc[e], m, 64);
    }
    if (lane == 0) {
#pragma unroll
        for (int e = 0; e < NEXP; e++)
            acc[e] += isf32 ? ((const float*)rbv_)[e] : bf2f(((const unsigned short*)rbv_)[e]);
        int i1 = 0; float v1 = acc[0];
#pragma unroll
        for (int e = 1; e < NEXP; e++) if (acc[e] > v1) { v1 = acc[e]; i1 = e; }
        int i2 = -1; float v2 = -3.4e38f;
#pragma unroll
        for (int e = 0; e < NEXP; e++) if (e != i1 && acc[e] > v2) { v2 = acc[e]; i2 = e; }
        float g1 = 1.f / (1.f + __expf(v2 - v1));
        float g2 = 1.f - g1;
        topkE[t] = i1 | (i2 << 8);
        float2 g; g.x = g1; g.y = g2;
        topkG[t] = g;
    }
}

// ---------------------------------------------------------------------------
// segcnt: 256 threads, parallel scan + shuffle/LDS reduce (no global atomics),
// padded segments + shared segments, pad-slot zeroing, 64B-padded fill bases.
// ---------------------------------------------------------------------------
__global__ __launch_bounds__(256) void segcnt_kernel(
    const int* __restrict__ topkE, int T,
    int* __restrict__ fill, int2* __restrict__ segdesc,
    int* __restrict__ nsegR, int* __restrict__ nsegAll,
    int* __restrict__ toklist, float* __restrict__ slotgate)
{
    __shared__ int hist[NEXP];
    const int tid = threadIdx.x;
    if (tid < NEXP) hist[tid] = 0;
    __syncthreads();
    int c[NEXP];
#pragma unroll
    for (int e = 0; e < NEXP; e++) c[e] = 0;
    for (int i = tid; i < T; i += 256) {
        int pk = topkE[i];
        int e0 = pk & 255, e1 = pk >> 8;
#pragma unroll
        for (int e = 0; e < NEXP; e++) c[e] += (e0 == e) + (e1 == e);
    }
#pragma unroll
    for (int m = 32; m >= 1; m >>= 1) {
#pragma unroll
        for (int e = 0; e < NEXP; e++) c[e] += __shfl_xor(c[e], m, 64);
    }
    if ((tid & 63) == 0) {
#pragma unroll
        for (int e = 0; e < NEXP; e++) atomicAdd(&hist[e], c[e]);
    }
    __syncthreads();
    int base[NEXP + 1];
    base[0] = 0;
#pragma unroll
    for (int e = 0; e < NEXP; e++) {
        int nsg = (hist[e] + BM - 1) / BM;
        base[e + 1] = base[e] + nsg * BM;
    }
    if (tid == 0) {
        int ns = 0;
        for (int e = 0; e < NEXP; e++)
            for (int b = base[e]; b < base[e + 1]; b += BM) {
                int2 s; s.x = e; s.y = b; segdesc[ns++] = s;
            }
        *nsegR = ns;
        for (int z = 0; z < 2; z++)
            for (int t0 = 0; t0 < T; t0 += BM) {
                int2 s; s.x = 8 + z; s.y = t0; segdesc[ns++] = s;
            }
        *nsegAll = ns;
    }
    if (tid < NEXP) fill[tid * 16] = base[tid];
    for (int e = 0; e < NEXP; e++)
        for (int i = base[e] + hist[e] + tid; i < base[e + 1]; i += 256) {
            toklist[i] = 0; slotgate[i] = 0.f;
        }
}

// ---------------------------------------------------------------------------
// gather: hierarchical slot assignment; records slotof per token.
// ---------------------------------------------------------------------------
__global__ __launch_bounds__(256) void gather_kernel(
    const int* __restrict__ topkE, const float2* __restrict__ topkG,
    int* __restrict__ fill, int* __restrict__ toklist,
    float* __restrict__ slotgate, int2* __restrict__ slotof, int T)
{
    __shared__ int hist[NEXP], sbase[NEXP], rank[NEXP];
    const int tid = threadIdx.x;
    if (tid < NEXP) { hist[tid] = 0; rank[tid] = 0; }
    __syncthreads();
    const int t = blockIdx.x * 256 + tid;
    int e0 = 0, e1 = 0; float2 g; g.x = 0.f; g.y = 0.f;
    const bool valid = (t < T);
    if (valid) {
        int pk = topkE[t]; g = topkG[t];
        e0 = pk & 255; e1 = pk >> 8;
        atomicAdd(&hist[e0], 1);
        atomicAdd(&hist[e1], 1);
    }
    __syncthreads();
    if (tid < NEXP) sbase[tid] = atomicAdd(&fill[tid * 16], hist[tid]);
    __syncthreads();
    if (valid) {
        int s0 = sbase[e0] + atomicAdd(&rank[e0], 1);
        int s1 = sbase[e1] + atomicAdd(&rank[e1], 1);
        toklist[s0] = t; slotgate[s0] = g.x;
        toklist[s1] = t; slotgate[s1] = g.y;
        int2 so; so.x = s0; so.y = s1;
        slotof[t] = so;
    }
}

// ---------------------------------------------------------------------------
// Unified hidden: e<8 routed (gathered rows, gate folded), e>=8 shared.
// 128x128 tile, 4 waves x (64x64 quadrant, 4x4 frags), dual acc.
// grid (MAXSEGH, H/128 = 4)
// ---------------------------------------------------------------------------
__global__ __launch_bounds__(256, 2) void moe_h_all_kernel(
    const void* __restrict__ x_, const unsigned short* __restrict__ xb,
    const unsigned short* __restrict__ w1t, const unsigned short* __restrict__ w3t,
    const int* __restrict__ flag, int useXb,
    const int* __restrict__ toklist, const float* __restrict__ slotgate,
    const int2* __restrict__ segdesc, const int* __restrict__ nsegAll,
    unsigned short* __restrict__ AbufSh, unsigned short* __restrict__ AbufRt)
{
    __shared__ __align__(16) unsigned short lA[BM][LDK];
    __shared__ __align__(16) unsigned short lB1[BN][LDK];
    __shared__ __align__(16) unsigned short lB3[BN][LDK];
    __shared__ int   lT[BM];
    __shared__ float lG[BM];

    const int s = blockIdx.x;
    if (s >= *nsegAll) return;
    const int tid = threadIdx.x;
    const int2 sd = segdesc[s];
    const int e = sd.x, slot0 = sd.y;
    const int n0 = blockIdx.y * BN;
    const unsigned short* W1 = w1t + (size_t)e * H_DIM * D_DIM;
    const unsigned short* W3 = w3t + (size_t)e * H_DIM * D_DIM;

    if (tid < BM) {
        if (e < 8) { lT[tid] = toklist[slot0 + tid]; lG[tid] = slotgate[slot0 + tid]; }
        else       { lT[tid] = slot0 + tid;          lG[tid] = 1.f; }
    }
    __syncthreads();

    floatx4 acc1[4][4], acc3[4][4];
#pragma unroll
    for (int fm = 0; fm < 4; fm++)
#pragma unroll
        for (int fn = 0; fn < 4; fn++) {
            floatx4 zz = {0.f, 0.f, 0.f, 0.f};
            acc1[fm][fn] = zz; acc3[fm][fn] = zz;
        }
    const int wave = tid >> 6, lane = tid & 63;
    const int wm = (wave >> 1) * 64, wn = (wave & 1) * 64;
    const int lm = lane & 15, lq = lane >> 4;

    const int isf32 = *flag;
    const unsigned short* xs = (isf32 && useXb) ? xb : (const unsigned short*)x_;
    const bool conv = (isf32 && !useXb);

    for (int k0 = 0; k0 < D_DIM; k0 += BK) {
        if (!conv) {
#pragma unroll
            for (int i = 0; i < 4; i++) {
                int m = (tid >> 3) + i * 32, kv = (tid & 7) * 8;
                *(uint4v*)&lA[m][kv] = *(const uint4v*)(xs + (size_t)lT[m] * D_DIM + k0 + kv);
            }
        } else {
            const float* xf = (const float*)x_;
#pragma unroll
            for (int i = 0; i < 4; i++) {
                int m = (tid >> 3) + i * 32, kv = (tid & 7) * 8;
                const float* src = xf + (size_t)lT[m] * D_DIM + k0 + kv;
                float4v a = *(const float4v*)src, b = *(const float4v*)(src + 4);
                uint4v v;
#pragma unroll
                for (int q = 0; q < 2; q++) {
                    v[q]     = (unsigned)f2bf(a[2 * q]) | ((unsigned)f2bf(a[2 * q + 1]) << 16);
                    v[q + 2] = (unsigned)f2bf(b[2 * q]) | ((unsigned)f2bf(b[2 * q + 1]) << 16);
                }
                *(uint4v*)&lA[m][kv] = v;
            }
        }
#pragma unroll
        for (int i = 0; i < 4; i++) {
            int n = (tid >> 3) + i * 32, kc = (tid & 7) * 8;
            *(uint4v*)&lB1[n][kc] = *(const uint4v*)(W1 + (size_t)(n0 + n) * D_DIM + k0 + kc);
            *(uint4v*)&lB3[n][kc] = *(const uint4v*)(W3 + (size_t)(n0 + n) * D_DIM + k0 + kc);
        }
        __syncthreads();
#pragma unroll
        for (int kk = 0; kk < BK; kk += 32) {
            short8 af[4], b1f[4], b3f[4];
#pragma unroll
            for (int fm = 0; fm < 4; fm++) af[fm] = *(const short8*)&lA[wm + fm * 16 + lm][kk + lq * 8];
#pragma unroll
            for (int fn = 0; fn < 4; fn++) {
                b1f[fn] = *(const short8*)&lB1[wn + fn * 16 + lm][kk + lq * 8];
                b3f[fn] = *(const short8*)&lB3[wn + fn * 16 + lm][kk + lq * 8];
            }
#pragma unroll
            for (int fm = 0; fm < 4; fm++)
#pragma unroll
                for (int fn = 0; fn < 4; fn++) {
                    acc1[fm][fn] = __builtin_amdgcn_mfma_f32_16x16x32_bf16(af[fm], b1f[fn], acc1[fm][fn], 0, 0, 0);
                    acc3[fm][fn] = __builtin_amdgcn_mfma_f32_16x16x32_bf16(af[fm], b3f[fn], acc3[fm][fn], 0, 0, 0);
                }
        }
        __syncthreads();
    }
#pragma unroll
    for (int fm = 0; fm < 4; fm++)
#pragma unroll
        for (int r = 0; r < 4; r++) {
            int row = wm + fm * 16 + lq * 4 + r;
            float g = lG[row];
#pragma unroll
            for (int fn = 0; fn < 4; fn++) {
                float a1 = acc1[fm][fn][r], a3 = acc3[fm][fn][r];
                float h = a1 / (1.f + __expf(-a1)) * a3 * g;
                int col = wn + fn * 16 + lm;
                if (e < 8)
                    AbufRt[(size_t)(slot0 + row) * H_DIM + n0 + col] = f2bf(h);
                else
                    AbufSh[(size_t)(slot0 + row) * (2 * H_DIM) + (e - 8) * H_DIM + n0 + col] = f2bf(h);
            }
        }
}

// ---------------------------------------------------------------------------
// Routed out: Or[slot,1024] = AbufRt[slot,512] @ w2_e (plain bf16 stores)
// 128x128 tile. grid (MAXSEGR, D/128 = 8)
// ---------------------------------------------------------------------------
__global__ __launch_bounds__(256, 3) void moe_out_routed_or_kernel(
    const unsigned short* __restrict__ Abuf, const unsigned short* __restrict__ w2t,
    const int2* __restrict__ segdesc, const int* __restrict__ nsegR,
    unsigned short* __restrict__ Or)
{
    __shared__ __align__(16) unsigned short lA[BM][LDK];
    __shared__ __align__(16) unsigned short lB[BN][LDK];

    const int s = blockIdx.x;
    if (s >= *nsegR) return;
    const int tid = threadIdx.x;
    const int2 sd = segdesc[s];
    const int e = sd.x, slot0 = sd.y;
    const int n0 = blockIdx.y * BN;
    const unsigned short* W2 = w2t + (size_t)e * D_DIM * H_DIM;

    floatx4 acc[4][4];
#pragma unroll
    for (int fm = 0; fm < 4; fm++)
#pragma unroll
        for (int fn = 0; fn < 4; fn++) { floatx4 zz = {0.f,0.f,0.f,0.f}; acc[fm][fn] = zz; }
    const int wave = tid >> 6, lane = tid & 63;
    const int wm = (wave >> 1) * 64, wn = (wave & 1) * 64;
    const int lm = lane & 15, lq = lane >> 4;

    for (int k0 = 0; k0 < H_DIM; k0 += BK) {
#pragma unroll
        for (int i = 0; i < 4; i++) {
            int m = (tid >> 3) + i * 32, kv = (tid & 7) * 8;
            *(uint4v*)&lA[m][kv] = *(const uint4v*)(Abuf + (size_t)(slot0 + m) * H_DIM + k0 + kv);
        }
#pragma unroll
        for (int i = 0; i < 4; i++) {
            int n = (tid >> 3) + i * 32, kc = (tid & 7) * 8;
            *(uint4v*)&lB[n][kc] = *(const uint4v*)(W2 + (size_t)(n0 + n) * H_DIM + k0 + kc);
        }
        __syncthreads();
#pragma unroll
        for (int kk = 0; kk < BK; kk += 32) {
            short8 af[4], bf[4];
#pragma unroll
            for (int fm = 0; fm < 4; fm++) af[fm] = *(const short8*)&lA[wm + fm * 16 + lm][kk + lq * 8];
#pragma unroll
            for (int fn = 0; fn < 4; fn++) bf[fn] = *(const short8*)&lB[wn + fn * 16 + lm][kk + lq * 8];
#pragma unroll
            for (int fm = 0; fm < 4; fm++)
#pragma unroll
                for (int fn = 0; fn < 4; fn++)
                    acc[fm][fn] = __builtin_amdgcn_mfma_f32_16x16x32_bf16(af[fm], bf[fn], acc[fm][fn], 0, 0, 0);
        }
        __syncthreads();
    }
#pragma unroll
    for (int fm = 0; fm < 4; fm++)
#pragma unroll
        for (int r = 0; r < 4; r++) {
            int row = wm + fm * 16 + lq * 4 + r;
#pragma unroll
            for (int fn = 0; fn < 4; fn++) {
                int col = wn + fn * 16 + lm;
                Or[(size_t)(slot0 + row) * D_DIM + n0 + col] = f2bf(acc[fm][fn][r]);
            }
        }
}

// ---------------------------------------------------------------------------
// Routed out fallback: atomic scatter into out (used only if ws too small)
// ---------------------------------------------------------------------------
__global__ __launch_bounds__(256, 3) void moe_out_routed_atomic_kernel(
    const unsigned short* __restrict__ Abuf, const unsigned short* __restrict__ w2t,
    const int2* __restrict__ segdesc, const int* __restrict__ nsegR,
    const int* __restrict__ toklist, const int* __restrict__ flag,
    void* __restrict__ out_)
{
    __shared__ __align__(16) unsigned short lA[BM][LDK];
    __shared__ __align__(16) unsigned short lB[BN][LDK];
    __shared__ int lT[BM];

    const int s = blockIdx.x;
    if (s >= *nsegR) return;
    const int isf32 = *flag;
    const int tid = threadIdx.x;
    const int2 sd = segdesc[s];
    const int e = sd.x, slot0 = sd.y;
    const int n0 = blockIdx.y * BN;
    const unsigned short* W2 = w2t + (size_t)e * D_DIM * H_DIM;

    if (tid < BM) lT[tid] = toklist[slot0 + tid];
    __syncthreads();

    floatx4 acc[4][4];
#pragma unroll
    for (int fm = 0; fm < 4; fm++)
#pragma unroll
        for (int fn = 0; fn < 4; fn++) { floatx4 zz = {0.f,0.f,0.f,0.f}; acc[fm][fn] = zz; }
    const int wave = tid >> 6, lane = tid & 63;
    const int wm = (wave >> 1) * 64, wn = (wave & 1) * 64;
    const int lm = lane & 15, lq = lane >> 4;

    for (int k0 = 0; k0 < H_DIM; k0 += BK) {
#pragma unroll
        for (int i = 0; i < 4; i++) {
            int m = (tid >> 3) + i * 32, kv = (tid & 7) * 8;
            *(uint4v*)&lA[m][kv] = *(const uint4v*)(Abuf + (size_t)(slot0 + m) * H_DIM + k0 + kv);
        }
#pragma unroll
        for (int i = 0; i < 4; i++) {
            int n = (tid >> 3) + i * 32, kc = (tid & 7) * 8;
            *(uint4v*)&lB[n][kc] = *(const uint4v*)(W2 + (size_t)(n0 + n) * H_DIM + k0 + kc);
        }
        __syncthreads();
#pragma unroll
        for (int kk = 0; kk < BK; kk += 32) {
            short8 af[4], bf[4];
#pragma unroll
            for (int fm = 0; fm < 4; fm++) af[fm] = *(const short8*)&lA[wm + fm * 16 + lm][kk + lq * 8];
#pragma unroll
            for (int fn = 0; fn < 4; fn++) bf[fn] = *(const short8*)&lB[wn + fn * 16 + lm][kk + lq * 8];
#pragma unroll
            for (int fm = 0; fm < 4; fm++)
#pragma unroll
                for (int fn = 0; fn < 4; fn++)
                    acc[fm][fn] = __builtin_amdgcn_mfma_f32_16x16x32_bf16(af[fm], bf[fn], acc[fm][fn], 0, 0, 0);
        }
        __syncthreads();
    }
#pragma unroll
    for (int fm = 0; fm < 4; fm++)
#pragma unroll
        for (int r = 0; r < 4; r++) {
            int row = wm + fm * 16 + lq * 4 + r;
            int t = lT[row];
#pragma unroll
            for (int fn = 0; fn < 4; fn++) {
                int col = wn + fn * 16 + lm;
                float val = acc[fm][fn][r];
                if (isf32) atomicAdd((float*)out_ + (size_t)t * D_DIM + n0 + col, val);
                else       atomAddBf16((unsigned short*)out_ + (size_t)t * D_DIM + n0 + col, val);
            }
        }
}

// ---------------------------------------------------------------------------
// Shared out (+fused routed combine): out[t] = AbufSh[t]@sw2cat (+Or[s0]+Or[s1])
// 128x128 tile. grid (T/128, D/128 = 8)
// ---------------------------------------------------------------------------
__global__ __launch_bounds__(256, 3) void moe_out_shared_kernel(
    const unsigned short* __restrict__ Abuf, const unsigned short* __restrict__ w2t,
    const int* __restrict__ flag, int fused,
    const unsigned short* __restrict__ Or, const int2* __restrict__ slotof,
    void* __restrict__ out_)
{
    __shared__ __align__(16) unsigned short lA[BM][LDK];
    __shared__ __align__(16) unsigned short lB[BN][LDK];
    __shared__ int2 lS[BM];

    const int isf32 = *flag;
    const int tid = threadIdx.x;
    const int t0 = blockIdx.x * BM, n0 = blockIdx.y * BN;

    if (fused && tid < BM) lS[tid] = slotof[t0 + tid];
    __syncthreads();

    floatx4 acc[4][4];
#pragma unroll
    for (int fm = 0; fm < 4; fm++)
#pragma unroll
        for (int fn = 0; fn < 4; fn++) { floatx4 zz = {0.f,0.f,0.f,0.f}; acc[fm][fn] = zz; }
    const int wave = tid >> 6, lane = tid & 63;
    const int wm = (wave >> 1) * 64, wn = (wave & 1) * 64;
    const int lm = lane & 15, lq = lane >> 4;

    for (int k0 = 0; k0 < 2 * H_DIM; k0 += BK) {
        const unsigned short* W2 = w2t + (size_t)(8 + (k0 >> 9)) * D_DIM * H_DIM;
        const int kk0 = k0 & (H_DIM - 1);
#pragma unroll
        for (int i = 0; i < 4; i++) {
            int m = (tid >> 3) + i * 32, kv = (tid & 7) * 8;
            *(uint4v*)&lA[m][kv] = *(const uint4v*)(Abuf + (size_t)(t0 + m) * (2 * H_DIM) + k0 + kv);
        }
#pragma unroll
        for (int i = 0; i < 4; i++) {
            int n = (tid >> 3) + i * 32, kc = (tid & 7) * 8;
            *(uint4v*)&lB[n][kc] = *(const uint4v*)(W2 + (size_t)(n0 + n) * H_DIM + kk0 + kc);
        }
        __syncthreads();
#pragma unroll
        for (int kk = 0; kk < BK; kk += 32) {
            short8 af[4], bf[4];
#pragma unroll
            for (int fm = 0; fm < 4; fm++) af[fm] = *(const short8*)&lA[wm + fm * 16 + lm][kk + lq * 8];
#pragma unroll
            for (int fn = 0; fn < 4; fn++) bf[fn] = *(const short8*)&lB[wn + fn * 16 + lm][kk + lq * 8];
#pragma unroll
            for (int fm = 0; fm < 4; fm++)
#pragma unroll
                for (int fn = 0; fn < 4; fn++)
                    acc[fm][fn] = __builtin_amdgcn_mfma_f32_16x16x32_bf16(af[fm], bf[fn], acc[fm][fn], 0, 0, 0);
        }
        __syncthreads();
    }
#pragma unroll
    for (int fm = 0; fm < 4; fm++)
#pragma unroll
        for (int r = 0; r < 4; r++) {
            int row = wm + fm * 16 + lq * 4 + r;
            int2 so; so.x = 0; so.y = 0;
            if (fused) so = lS[row];
#pragma unroll
            for (int fn = 0; fn < 4; fn++) {
                int col = wn + fn * 16 + lm;
                float val = acc[fm][fn][r];
                if (fused) {
                    val += bf2f(Or[(size_t)so.x * D_DIM + n0 + col]);
                    val += bf2f(Or[(size_t)so.y * D_DIM + n0 + col]);
                }
                size_t off = (size_t)(t0 + row) * D_DIM + n0 + col;
                if (isf32) ((float*)out_)[off] = val;
                else       ((unsigned short*)out_)[off] = f2bf(val);
            }
        }
}

// ---------------------------------------------------------------------------
extern "C" void kernel_launch(void* const* d_in, const int* in_sizes, int n_in,
                              void* d_out, int out_size, void* d_ws, size_t ws_size,
                              hipStream_t stream)
{
    const void* x   = d_in[0];
    const void* rw  = d_in[1];
    const void* rb  = d_in[2];
    const void* rw1 = d_in[3];
    const void* rw3 = d_in[4];
    const void* rw2 = d_in[5];
    const void* sw1 = d_in[6];
    const void* sw3 = d_in[7];
    const void* sw2 = d_in[8];

    const int T = in_sizes[0] / D_DIM;          // 4096
    const int SLOT_MAX = 2 * T + NEXP * BM;     // 9216
    const int MAXSEGR  = SLOT_MAX / BM;         // 72
    const int MAXSEGH  = MAXSEGR + 2 * (T / BM);// 136

    char* p = (char*)d_ws;
    int*    flag     = (int*)p;
    int*    nsegR    = (int*)(p + 64);
    int*    nsegAll  = (int*)(p + 96);
    int*    fill     = (int*)(p + 128);         // 8 x 16 ints (64B padded)
    int2*   segdesc  = (int2*)(p + 1024);       // up to 136 segs
    size_t  o = 4096;
    int*    topkE    = (int*)(p + o);    o += (size_t)4 * T;
    float2* topkG    = (float2*)(p + o); o += (size_t)8 * T;
    int2*   slotof   = (int2*)(p + o);   o += (size_t)8 * T;
    int*    toklist  = (int*)(p + o);    o += (size_t)4 * SLOT_MAX;
    float*  slotgate = (float*)(p + o);  o += (size_t)4 * SLOT_MAX;
    o = (o + 255) & ~(size_t)255;
    // layout: w1t | AbufSh | AbufRt | w3t | xb   (w3t+xb reused as Or; w1t as w2t)
    unsigned short* w1t    = (unsigned short*)(p + o); o += (size_t)NP * H_DIM * D_DIM * 2;
    unsigned short* AbufSh = (unsigned short*)(p + o); o += (size_t)T * (2 * H_DIM) * 2;
    unsigned short* AbufRt = (unsigned short*)(p + o); o += (size_t)SLOT_MAX * H_DIM * 2;
    unsigned short* w3t    = (unsigned short*)(p + o); o += (size_t)NP * H_DIM * D_DIM * 2;
    unsigned short* xb     = (unsigned short*)(p + o);
    const size_t REQ = o + (size_t)T * D_DIM * 2;   // ~47.35 MB
    const int fast = (ws_size >= REQ) ? 1 : 0;
    unsigned short* w2t = w1t;   // overlay: w1t dead after h_all
    unsigned short* Or  = w3t;   // overlay: w3t+xb (18.87MB) dead after h_all

    detect_kernel<<<1, 256, 0, stream>>>((const unsigned short*)x, flag);
    transp13_kernel<<<dim3(D_DIM / 32, H_DIM / 64, 2 * NP), 256, 0, stream>>>(
        rw1, rw3, sw1, sw3, w1t, w3t, flag);
    router_kernel<<<T / 4, 256, 0, stream>>>(x, rw, rb, flag, topkE, topkG, xb, fast, T);
    segcnt_kernel<<<1, 256, 0, stream>>>(topkE, T, fill, segdesc, nsegR, nsegAll, toklist, slotgate);
    gather_kernel<<<(T + 255) / 256, 256, 0, stream>>>(topkE, topkG, fill, toklist, slotgate, slotof, T);
    moe_h_all_kernel<<<dim3(MAXSEGH, H_DIM / BN), 256, 0, stream>>>(
        x, xb, w1t, w3t, flag, fast, toklist, slotgate, segdesc, nsegAll, AbufSh, AbufRt);
    transp_kernel<<<dim3(H_DIM / 32, D_DIM / 64, NP), 256, 0, stream>>>(rw2, sw2, w2t, H_DIM, D_DIM, flag);
    if (fast) {
        moe_out_routed_or_kernel<<<dim3(MAXSEGR, D_DIM / BN), 256, 0, stream>>>(
            AbufRt, w2t, segdesc, nsegR, Or);
        moe_out_shared_kernel<<<dim3(T / BM, D_DIM / BN), 256, 0, stream>>>(
            AbufSh, w2t, flag, 1, Or, slotof, d_out);
    } else {
        moe_out_shared_kernel<<<dim3(T / BM, D_DIM / BN), 256, 0, stream>>>(
            AbufSh, w2t, flag, 0, nullptr, nullptr, d_out);
        moe_out_routed_atomic_kernel<<<dim3(MAXSEGR, D_DIM / BN), 256, 0, stream>>>(
            AbufRt, w2t, segdesc, nsegR, toklist, flag, d_out);
    }
}

// Round 8
// 278.459 us; speedup vs baseline: 1.2248x; 1.2248x over previous
//
#include <hip/hip_runtime.h>
#include <stdint.h>

#define D_DIM 1024
#define H_DIM 512
#define NEXP  8
#define NP    10            // 8 routed + 2 shared expert passes

#define BM 128
#define BK 64
#define LDK 72              // padded stride (fallback atomic kernel only)

typedef __attribute__((ext_vector_type(8))) short short8;     // 8 bf16 MFMA operand
typedef __attribute__((ext_vector_type(4))) float floatx4;    // MFMA accumulator
typedef __attribute__((ext_vector_type(4))) unsigned int uint4v;
typedef __attribute__((ext_vector_type(4))) float float4v;

typedef __attribute__((address_space(3))) unsigned char* as3p;
typedef const __attribute__((address_space(1))) unsigned char* as1p;

__device__ __forceinline__ void async16(void* lds, const void* g) {
    // wave-uniform LDS base; HW scatters lane i -> lds + i*16
    __builtin_amdgcn_global_load_lds((as1p)g, (as3p)lds, 16, 0, 0);
}

__device__ __forceinline__ float bf2f(unsigned short u) {
    union { float f; unsigned int i; } v; v.i = ((unsigned int)u) << 16; return v.f;
}
__device__ __forceinline__ unsigned short f2bf(float f) {
    union { float f; unsigned int i; } v; v.f = f;
    unsigned int r = v.i + 0x7FFFu + ((v.i >> 16) & 1u);   // RNE
    return (unsigned short)(r >> 16);
}

// bf16 atomic add via CAS (fallback path only)
__device__ void atomAddBf16(unsigned short* pp, float v) {
    unsigned int* w = (unsigned int*)((size_t)pp & ~(size_t)3);
    const bool hi = ((size_t)pp & 2) != 0;
    unsigned int old = *w, assumed;
    do {
        assumed = old;
        unsigned short cur = hi ? (unsigned short)(assumed >> 16)
                                : (unsigned short)(assumed & 0xFFFFu);
        unsigned short nv = f2bf(bf2f(cur) + v);
        unsigned int repl = hi ? ((assumed & 0x0000FFFFu) | ((unsigned)nv << 16))
                               : ((assumed & 0xFFFF0000u) | nv);
        old = atomicCAS(w, assumed, repl);
    } while (old != assumed);
}

// ---------------------------------------------------------------------------
__global__ void detect_kernel(const unsigned short* __restrict__ x, int* flag)
{
    __shared__ int bad;
    if (threadIdx.x == 0) bad = 0;
    __syncthreads();
    int b = 0;
    for (int i = threadIdx.x; i < 8192; i += 256) {
        int e = (x[i] >> 7) & 0xFF;
        if (e >= 0xA0) b = 1;
    }
    if (b) atomicOr(&bad, 1);
    __syncthreads();
    if (threadIdx.x == 0) *flag = bad;
}

// ---------------------------------------------------------------------------
// w1 + w3 transpose+convert: z 0..9 -> w1t, z 10..19 -> w3t  ([K][N]->[N][K])
// ---------------------------------------------------------------------------
__global__ __launch_bounds__(256) void transp13_kernel(
    const void* __restrict__ rw1, const void* __restrict__ rw3,
    const void* __restrict__ sw1, const void* __restrict__ sw3,
    unsigned short* __restrict__ w1t, unsigned short* __restrict__ w3t,
    const int* __restrict__ flag)
{
    const int isf32 = *flag;
    const int z = blockIdx.z;
    const int grp = z / 10, zz = z % 10;
    const void* src_ = grp == 0 ? (zz < 8 ? rw1 : sw1) : (zz < 8 ? rw3 : sw3);
    unsigned short* dstB = grp == 0 ? w1t : w3t;
    const size_t moff = (size_t)(zz < 8 ? zz : zz - 8) * D_DIM * H_DIM;
    const int nl = threadIdx.x & 63, j = threadIdx.x >> 6;
    const int n = blockIdx.y * 64 + nl;
    const int k0 = blockIdx.x * 32 + j * 8;

    unsigned short v[8];
    if (isf32) {
        const float* src = (const float*)src_ + moff;
#pragma unroll
        for (int j2 = 0; j2 < 8; j2++) v[j2] = f2bf(src[(size_t)(k0 + j2) * H_DIM + n]);
    } else {
        const unsigned short* src = (const unsigned short*)src_ + moff;
#pragma unroll
        for (int j2 = 0; j2 < 8; j2++) v[j2] = src[(size_t)(k0 + j2) * H_DIM + n];
    }
    uint4v w;
#pragma unroll
    for (int q = 0; q < 4; q++) w[q] = (unsigned)v[2 * q] | ((unsigned)v[2 * q + 1] << 16);
    *(uint4v*)(dstB + ((size_t)zz * H_DIM + n) * D_DIM + k0) = w;
}

// ---------------------------------------------------------------------------
// Generic transpose (w2): src [nmat][K][N] -> dst bf16 [nmat][N][K]
// ---------------------------------------------------------------------------
__global__ __launch_bounds__(256) void transp_kernel(
    const void* __restrict__ rsrc, const void* __restrict__ ssrc,
    unsigned short* __restrict__ dst, int K, int N, const int* __restrict__ flag)
{
    const int isf32 = *flag;
    const int z = blockIdx.z;
    const size_t moff = (size_t)(z < 8 ? z : z - 8) * K * N;
    const int nl = threadIdx.x & 63, j = threadIdx.x >> 6;
    const int n = blockIdx.y * 64 + nl;
    const int k0 = blockIdx.x * 32 + j * 8;

    unsigned short v[8];
    if (isf32) {
        const float* src = (const float*)(z < 8 ? rsrc : ssrc) + moff;
#pragma unroll
        for (int j2 = 0; j2 < 8; j2++) v[j2] = f2bf(src[(size_t)(k0 + j2) * N + n]);
    } else {
        const unsigned short* src = (const unsigned short*)(z < 8 ? rsrc : ssrc) + moff;
#pragma unroll
        for (int j2 = 0; j2 < 8; j2++) v[j2] = src[(size_t)(k0 + j2) * N + n];
    }
    uint4v w;
#pragma unroll
    for (int q = 0; q < 4; q++) w[q] = (unsigned)v[2 * q] | ((unsigned)v[2 * q + 1] << 16);
    *(uint4v*)(dst + ((size_t)z * N + n) * K + k0) = w;
}

// ---------------------------------------------------------------------------
// Router: one wave per token -> top-2 ids + gates; fp32 mode also emits bf16 xb.
// ---------------------------------------------------------------------------
__global__ __launch_bounds__(256, 4) void router_kernel(
    const void* __restrict__ xv_, const void* __restrict__ rwv_,
    const void* __restrict__ rbv_, const int* __restrict__ flag,
    int* __restrict__ topkE, float2* __restrict__ topkG,
    unsigned short* __restrict__ xb, int useXb, int T)
{
    const int isf32 = *flag;
    int gid  = blockIdx.x * blockDim.x + threadIdx.x;
    int t    = gid >> 6;
    int lane = threadIdx.x & 63;
    if (t >= T) return;

    float acc[NEXP];
#pragma unroll
    for (int e = 0; e < NEXP; e++) acc[e] = 0.f;

    if (isf32) {
        const float* xr = (const float*)xv_ + (size_t)t * D_DIM;
        const float* rw = (const float*)rwv_;
        unsigned short* xo = xb + (size_t)t * D_DIM;
#pragma unroll 4
        for (int i = 0; i < D_DIM / 64; i++) {
            int d = i * 64 + lane;
            float xv = xr[d];
            if (useXb) xo[d] = f2bf(xv);
            float4v wa = *(const float4v*)(rw + (size_t)d * NEXP);
            float4v wb = *(const float4v*)(rw + (size_t)d * NEXP + 4);
#pragma unroll
            for (int q = 0; q < 4; q++) { acc[q] += xv * wa[q]; acc[q + 4] += xv * wb[q]; }
        }
    } else {
        const unsigned short* xr = (const unsigned short*)xv_ + (size_t)t * D_DIM;
        const unsigned short* rw = (const unsigned short*)rwv_;
#pragma unroll 4
        for (int i = 0; i < D_DIM / 64; i++) {
            int d = i * 64 + lane;
            float xv = bf2f(xr[d]);
            uint4v wv = *(const uint4v*)(rw + (size_t)d * NEXP);
#pragma unroll
            for (int q = 0; q < 4; q++) {
                unsigned int w = wv[q];
                acc[q * 2 + 0] += xv * bf2f((unsigned short)(w & 0xFFFFu));
                acc[q * 2 + 1] += xv * bf2f((unsigned short)(w >> 16));
            }
        }
    }
#pragma unroll
    for (int m = 32; m >= 1; m >>= 1) {
#pragma unroll
        for (int e = 0; e < NEXP; e++) acc[e] += __shfl_xor(acc[e], m, 64);
    }
    if (lane == 0) {
#pragma unroll
        for (int e = 0; e < NEXP; e++)
            acc[e] += isf32 ? ((const float*)rbv_)[e] : bf2f(((const unsigned short*)rbv_)[e]);
        int i1 = 0; float v1 = acc[0];
#pragma unroll
        for (int e = 1; e < NEXP; e++) if (acc[e] > v1) { v1 = acc[e]; i1 = e; }
        int i2 = -1; float v2 = -3.4e38f;
#pragma unroll
        for (int e = 0; e < NEXP; e++) if (e != i1 && acc[e] > v2) { v2 = acc[e]; i2 = e; }
        float g1 = 1.f / (1.f + __expf(v2 - v1));
        float g2 = 1.f - g1;
        topkE[t] = i1 | (i2 << 8);
        float2 g; g.x = g1; g.y = g2;
        topkG[t] = g;
    }
}

// ---------------------------------------------------------------------------
// segcnt: 256 threads, LDS-reduced histogram, padded routed segments + shared
// segments, pad-slot zeroing, 64B-padded fill bases.
// ---------------------------------------------------------------------------
__global__ __launch_bounds__(256) void segcnt_kernel(
    const int* __restrict__ topkE, int T,
    int* __restrict__ fill, int2* __restrict__ segdesc,
    int* __restrict__ nsegR, int* __restrict__ nsegAll,
    int* __restrict__ toklist, float* __restrict__ slotgate)
{
    __shared__ int hist[NEXP];
    const int tid = threadIdx.x;
    if (tid < NEXP) hist[tid] = 0;
    __syncthreads();
    int c[NEXP];
#pragma unroll
    for (int e = 0; e < NEXP; e++) c[e] = 0;
    for (int i = tid; i < T; i += 256) {
        int pk = topkE[i];
        int e0 = pk & 255, e1 = pk >> 8;
#pragma unroll
        for (int e = 0; e < NEXP; e++) c[e] += (e0 == e) + (e1 == e);
    }
#pragma unroll
    for (int m = 32; m >= 1; m >>= 1) {
#pragma unroll
        for (int e = 0; e < NEXP; e++) c[e] += __shfl_xor(c[e], m, 64);
    }
    if ((tid & 63) == 0) {
#pragma unroll
        for (int e = 0; e < NEXP; e++) atomicAdd(&hist[e], c[e]);
    }
    __syncthreads();
    int base[NEXP + 1];
    base[0] = 0;
#pragma unroll
    for (int e = 0; e < NEXP; e++) {
        int nsg = (hist[e] + BM - 1) / BM;
        base[e + 1] = base[e] + nsg * BM;
    }
    if (tid == 0) {
        int ns = 0;
        for (int e = 0; e < NEXP; e++)
            for (int b = base[e]; b < base[e + 1]; b += BM) {
                int2 s; s.x = e; s.y = b; segdesc[ns++] = s;
            }
        *nsegR = ns;
        for (int z = 0; z < 2; z++)
            for (int t0 = 0; t0 < T; t0 += BM) {
                int2 s; s.x = 8 + z; s.y = t0; segdesc[ns++] = s;
            }
        *nsegAll = ns;
    }
    if (tid < NEXP) fill[tid * 16] = base[tid];
    for (int e = 0; e < NEXP; e++)
        for (int i = base[e] + hist[e] + tid; i < base[e + 1]; i += 256) {
            toklist[i] = 0; slotgate[i] = 0.f;
        }
}

// ---------------------------------------------------------------------------
// gather: hierarchical slot assignment; records slotof per token.
// ---------------------------------------------------------------------------
__global__ __launch_bounds__(256) void gather_kernel(
    const int* __restrict__ topkE, const float2* __restrict__ topkG,
    int* __restrict__ fill, int* __restrict__ toklist,
    float* __restrict__ slotgate, int2* __restrict__ slotof, int T)
{
    __shared__ int hist[NEXP], sbase[NEXP], rank[NEXP];
    const int tid = threadIdx.x;
    if (tid < NEXP) { hist[tid] = 0; rank[tid] = 0; }
    __syncthreads();
    const int t = blockIdx.x * 256 + tid;
    int e0 = 0, e1 = 0; float2 g; g.x = 0.f; g.y = 0.f;
    const bool valid = (t < T);
    if (valid) {
        int pk = topkE[t]; g = topkG[t];
        e0 = pk & 255; e1 = pk >> 8;
        atomicAdd(&hist[e0], 1);
        atomicAdd(&hist[e1], 1);
    }
    __syncthreads();
    if (tid < NEXP) sbase[tid] = atomicAdd(&fill[tid * 16], hist[tid]);
    __syncthreads();
    if (valid) {
        int s0 = sbase[e0] + atomicAdd(&rank[e0], 1);
        int s1 = sbase[e1] + atomicAdd(&rank[e1], 1);
        toklist[s0] = t; slotgate[s0] = g.x;
        toklist[s1] = t; slotgate[s1] = g.y;
        int2 so; so.x = s0; so.y = s1;
        slotof[t] = so;
    }
}

// ---------------------------------------------------------------------------
// Unified hidden: 128x64 tile, dual acc, global_load_lds + XOR-swizzled LDS.
// LDS row = 64 elems (128B, no pad). Granule g of row r stored at pos g^(r&7).
// grid (MAXSEGH, H/64 = 8)
// ---------------------------------------------------------------------------
__global__ __launch_bounds__(256, 4) void moe_h_all_kernel(
    const void* __restrict__ x_, const unsigned short* __restrict__ xb,
    const unsigned short* __restrict__ w1t, const unsigned short* __restrict__ w3t,
    const int* __restrict__ flag, int useXb,
    const int* __restrict__ toklist, const float* __restrict__ slotgate,
    const int2* __restrict__ segdesc, const int* __restrict__ nsegAll,
    unsigned short* __restrict__ AbufSh, unsigned short* __restrict__ AbufRt)
{
    __shared__ __align__(16) unsigned short lA[BM][64];
    __shared__ __align__(16) unsigned short lB1[64][64];
    __shared__ __align__(16) unsigned short lB3[64][64];
    __shared__ int   lT[BM];
    __shared__ float lG[BM];

    const int s = blockIdx.x;
    if (s >= *nsegAll) return;
    const int tid = threadIdx.x;
    const int2 sd = segdesc[s];
    const int e = sd.x, slot0 = sd.y;
    const int n0 = blockIdx.y * 64;
    const unsigned short* W1 = w1t + (size_t)e * H_DIM * D_DIM;
    const unsigned short* W3 = w3t + (size_t)e * H_DIM * D_DIM;

    if (tid < BM) {
        if (e < 8) { lT[tid] = toklist[slot0 + tid]; lG[tid] = slotgate[slot0 + tid]; }
        else       { lT[tid] = slot0 + tid;          lG[tid] = 1.f; }
    }
    __syncthreads();

    const int wave = tid >> 6, lane = tid & 63;
    const int wm = (wave >> 1) * 64, wn = (wave & 1) * 32;
    const int lm = lane & 15, lq = lane >> 4;
    const int sw = (lane & 7) ^ ((lane >> 3) & 7);   // source granule for my slot

    const int isf32 = *flag;
    const unsigned short* xs = (isf32 && useXb) ? xb : (const unsigned short*)x_;
    const bool conv = (isf32 && !useXb);

    // precompute per-thread async source bases (minus k0)
    const unsigned short* aSrc[4];
    const unsigned short* b1Src[2];
    const unsigned short* b3Src[2];
    if (!conv) {
#pragma unroll
        for (int j = 0; j < 4; j++) {
            int r = (4 * wave + j) * 8 + (lane >> 3);
            aSrc[j] = xs + (size_t)lT[r] * D_DIM + sw * 8;
        }
    }
#pragma unroll
    for (int j = 0; j < 2; j++) {
        int r = (2 * wave + j) * 8 + (lane >> 3);
        b1Src[j] = W1 + (size_t)(n0 + r) * D_DIM + sw * 8;
        b3Src[j] = W3 + (size_t)(n0 + r) * D_DIM + sw * 8;
    }
    unsigned short* lAf  = &lA[0][0];
    unsigned short* lB1f = &lB1[0][0];
    unsigned short* lB3f = &lB3[0][0];

    floatx4 acc1[4][2], acc3[4][2];
#pragma unroll
    for (int fm = 0; fm < 4; fm++)
#pragma unroll
        for (int fn = 0; fn < 2; fn++) {
            floatx4 zz = {0.f, 0.f, 0.f, 0.f};
            acc1[fm][fn] = zz; acc3[fm][fn] = zz;
        }

    for (int k0 = 0; k0 < D_DIM; k0 += BK) {
        if (!conv) {
#pragma unroll
            for (int j = 0; j < 4; j++)
                async16(lAf + (4 * wave + j) * 512, aSrc[j] + k0);
        } else {
            const float* xf = (const float*)x_;
#pragma unroll
            for (int i = 0; i < 4; i++) {
                int m = (tid >> 3) + i * 32, pos = (tid & 7);
                int gsrc = pos ^ (m & 7);
                const float* src = xf + (size_t)lT[m] * D_DIM + k0 + gsrc * 8;
                float4v a = *(const float4v*)src, b = *(const float4v*)(src + 4);
                uint4v v;
#pragma unroll
                for (int q = 0; q < 2; q++) {
                    v[q]     = (unsigned)f2bf(a[2 * q]) | ((unsigned)f2bf(a[2 * q + 1]) << 16);
                    v[q + 2] = (unsigned)f2bf(b[2 * q]) | ((unsigned)f2bf(b[2 * q + 1]) << 16);
                }
                *(uint4v*)&lA[m][pos * 8] = v;
            }
        }
#pragma unroll
        for (int j = 0; j < 2; j++) {
            async16(lB1f + (2 * wave + j) * 512, b1Src[j] + k0);
            async16(lB3f + (2 * wave + j) * 512, b3Src[j] + k0);
        }
        __syncthreads();
#pragma unroll
        for (int kk = 0; kk < BK; kk += 32) {
            const int p8 = (((kk >> 3) + lq) ^ (lm & 7)) * 8;
            short8 af[4], b1f[2], b3f[2];
#pragma unroll
            for (int fm = 0; fm < 4; fm++)
                af[fm] = *(const short8*)&lA[wm + fm * 16 + lm][p8];
#pragma unroll
            for (int fn = 0; fn < 2; fn++) {
                b1f[fn] = *(const short8*)&lB1[wn + fn * 16 + lm][p8];
                b3f[fn] = *(const short8*)&lB3[wn + fn * 16 + lm][p8];
            }
#pragma unroll
            for (int fm = 0; fm < 4; fm++)
#pragma unroll
                for (int fn = 0; fn < 2; fn++) {
                    acc1[fm][fn] = __builtin_amdgcn_mfma_f32_16x16x32_bf16(af[fm], b1f[fn], acc1[fm][fn], 0, 0, 0);
                    acc3[fm][fn] = __builtin_amdgcn_mfma_f32_16x16x32_bf16(af[fm], b3f[fn], acc3[fm][fn], 0, 0, 0);
                }
        }
        __syncthreads();
    }
#pragma unroll
    for (int fm = 0; fm < 4; fm++)
#pragma unroll
        for (int r = 0; r < 4; r++) {
            int row = wm + fm * 16 + lq * 4 + r;
            float g = lG[row];
#pragma unroll
            for (int fn = 0; fn < 2; fn++) {
                float a1 = acc1[fm][fn][r], a3 = acc3[fm][fn][r];
                float h = a1 / (1.f + __expf(-a1)) * a3 * g;
                int col = wn + fn * 16 + lm;
                if (e < 8)
                    AbufRt[(size_t)(slot0 + row) * H_DIM + n0 + col] = f2bf(h);
                else
                    AbufSh[(size_t)(slot0 + row) * (2 * H_DIM) + (e - 8) * H_DIM + n0 + col] = f2bf(h);
            }
        }
}

// ---------------------------------------------------------------------------
// Routed out: Or[slot,1024] = AbufRt[slot,512] @ w2_e. 128x128 tile, single
// acc, async+swizzle staging. grid (MAXSEGR, D/128 = 8)
// ---------------------------------------------------------------------------
__global__ __launch_bounds__(256, 4) void moe_out_routed_or_kernel(
    const unsigned short* __restrict__ Abuf, const unsigned short* __restrict__ w2t,
    const int2* __restrict__ segdesc, const int* __restrict__ nsegR,
    unsigned short* __restrict__ Or)
{
    __shared__ __align__(16) unsigned short lA[BM][64];
    __shared__ __align__(16) unsigned short lB[128][64];

    const int s = blockIdx.x;
    if (s >= *nsegR) return;
    const int tid = threadIdx.x;
    const int2 sd = segdesc[s];
    const int e = sd.x, slot0 = sd.y;
    const int n0 = blockIdx.y * 128;
    const unsigned short* W2 = w2t + (size_t)e * D_DIM * H_DIM;

    const int wave = tid >> 6, lane = tid & 63;
    const int wm = (wave >> 1) * 64, wn = (wave & 1) * 64;
    const int lm = lane & 15, lq = lane >> 4;
    const int sw = (lane & 7) ^ ((lane >> 3) & 7);

    const unsigned short* aSrc[4];
    const unsigned short* bSrc[4];
#pragma unroll
    for (int j = 0; j < 4; j++) {
        int r = (4 * wave + j) * 8 + (lane >> 3);
        aSrc[j] = Abuf + (size_t)(slot0 + r) * H_DIM + sw * 8;
        bSrc[j] = W2 + (size_t)(n0 + r) * H_DIM + sw * 8;
    }
    unsigned short* lAf = &lA[0][0];
    unsigned short* lBf = &lB[0][0];

    floatx4 acc[4][4];
#pragma unroll
    for (int fm = 0; fm < 4; fm++)
#pragma unroll
        for (int fn = 0; fn < 4; fn++) { floatx4 zz = {0.f,0.f,0.f,0.f}; acc[fm][fn] = zz; }

    for (int k0 = 0; k0 < H_DIM; k0 += BK) {
#pragma unroll
        for (int j = 0; j < 4; j++) {
            async16(lAf + (4 * wave + j) * 512, aSrc[j] + k0);
            async16(lBf + (4 * wave + j) * 512, bSrc[j] + k0);
        }
        __syncthreads();
#pragma unroll
        for (int kk = 0; kk < BK; kk += 32) {
            const int p8 = (((kk >> 3) + lq) ^ (lm & 7)) * 8;
            short8 af[4], bf[4];
#pragma unroll
            for (int fm = 0; fm < 4; fm++) af[fm] = *(const short8*)&lA[wm + fm * 16 + lm][p8];
#pragma unroll
            for (int fn = 0; fn < 4; fn++) bf[fn] = *(const short8*)&lB[wn + fn * 16 + lm][p8];
#pragma unroll
            for (int fm = 0; fm < 4; fm++)
#pragma unroll
                for (int fn = 0; fn < 4; fn++)
                    acc[fm][fn] = __builtin_amdgcn_mfma_f32_16x16x32_bf16(af[fm], bf[fn], acc[fm][fn], 0, 0, 0);
        }
        __syncthreads();
    }
#pragma unroll
    for (int fm = 0; fm < 4; fm++)
#pragma unroll
        for (int r = 0; r < 4; r++) {
            int row = wm + fm * 16 + lq * 4 + r;
#pragma unroll
            for (int fn = 0; fn < 4; fn++) {
                int col = wn + fn * 16 + lm;
                Or[(size_t)(slot0 + row) * D_DIM + n0 + col] = f2bf(acc[fm][fn][r]);
            }
        }
}

// ---------------------------------------------------------------------------
// Shared out (+fused routed combine): out[t] = AbufSh[t]@sw2cat + Or[s0]+Or[s1]
// 128x128 tile, async+swizzle. grid (T/128, D/128 = 8)
// ---------------------------------------------------------------------------
__global__ __launch_bounds__(256, 4) void moe_out_shared_kernel(
    const unsigned short* __restrict__ Abuf, const unsigned short* __restrict__ w2t,
    const int* __restrict__ flag, int fused,
    const unsigned short* __restrict__ Or, const int2* __restrict__ slotof,
    void* __restrict__ out_)
{
    __shared__ __align__(16) unsigned short lA[BM][64];
    __shared__ __align__(16) unsigned short lB[128][64];
    __shared__ int2 lS[BM];

    const int isf32 = *flag;
    const int tid = threadIdx.x;
    const int t0 = blockIdx.x * BM, n0 = blockIdx.y * 128;

    if (fused && tid < BM) lS[tid] = slotof[t0 + tid];
    __syncthreads();

    const int wave = tid >> 6, lane = tid & 63;
    const int wm = (wave >> 1) * 64, wn = (wave & 1) * 64;
    const int lm = lane & 15, lq = lane >> 4;
    const int sw = (lane & 7) ^ ((lane >> 3) & 7);

    const unsigned short* aSrc[4];
    size_t bRow[4];
#pragma unroll
    for (int j = 0; j < 4; j++) {
        int r = (4 * wave + j) * 8 + (lane >> 3);
        aSrc[j] = Abuf + (size_t)(t0 + r) * (2 * H_DIM) + sw * 8;
        bRow[j] = (size_t)(n0 + r) * H_DIM + sw * 8;
    }
    unsigned short* lAf = &lA[0][0];
    unsigned short* lBf = &lB[0][0];

    floatx4 acc[4][4];
#pragma unroll
    for (int fm = 0; fm < 4; fm++)
#pragma unroll
        for (int fn = 0; fn < 4; fn++) { floatx4 zz = {0.f,0.f,0.f,0.f}; acc[fm][fn] = zz; }

    for (int k0 = 0; k0 < 2 * H_DIM; k0 += BK) {
        const unsigned short* W2 = w2t + (size_t)(8 + (k0 >> 9)) * D_DIM * H_DIM;
        const int kk0 = k0 & (H_DIM - 1);
#pragma unroll
        for (int j = 0; j < 4; j++) {
            async16(lAf + (4 * wave + j) * 512, aSrc[j] + k0);
            async16(lBf + (4 * wave + j) * 512, W2 + bRow[j] + kk0);
        }
        __syncthreads();
#pragma unroll
        for (int kk = 0; kk < BK; kk += 32) {
            const int p8 = (((kk >> 3) + lq) ^ (lm & 7)) * 8;
            short8 af[4], bf[4];
#pragma unroll
            for (int fm = 0; fm < 4; fm++) af[fm] = *(const short8*)&lA[wm + fm * 16 + lm][p8];
#pragma unroll
            for (int fn = 0; fn < 4; fn++) bf[fn] = *(const short8*)&lB[wn + fn * 16 + lm][p8];
#pragma unroll
            for (int fm = 0; fm < 4; fm++)
#pragma unroll
                for (int fn = 0; fn < 4; fn++)
                    acc[fm][fn] = __builtin_amdgcn_mfma_f32_16x16x32_bf16(af[fm], bf[fn], acc[fm][fn], 0, 0, 0);
        }
        __syncthreads();
    }
#pragma unroll
    for (int fm = 0; fm < 4; fm++)
#pragma unroll
        for (int r = 0; r < 4; r++) {
            int row = wm + fm * 16 + lq * 4 + r;
            int2 so; so.x = 0; so.y = 0;
            if (fused) so = lS[row];
#pragma unroll
            for (int fn = 0; fn < 4; fn++) {
                int col = wn + fn * 16 + lm;
                float val = acc[fm][fn][r];
                if (fused) {
                    val += bf2f(Or[(size_t)so.x * D_DIM + n0 + col]);
                    val += bf2f(Or[(size_t)so.y * D_DIM + n0 + col]);
                }
                size_t off = (size_t)(t0 + row) * D_DIM + n0 + col;
                if (isf32) ((float*)out_)[off] = val;
                else       ((unsigned short*)out_)[off] = f2bf(val);
            }
        }
}

// ---------------------------------------------------------------------------
// Routed out fallback (ws too small): atomic scatter, padded-LDS staging.
// ---------------------------------------------------------------------------
__global__ __launch_bounds__(256, 3) void moe_out_routed_atomic_kernel(
    const unsigned short* __restrict__ Abuf, const unsigned short* __restrict__ w2t,
    const int2* __restrict__ segdesc, const int* __restrict__ nsegR,
    const int* __restrict__ toklist, const int* __restrict__ flag,
    void* __restrict__ out_)
{
    __shared__ __align__(16) unsigned short lA[BM][LDK];
    __shared__ __align__(16) unsigned short lB[64][LDK];
    __shared__ int lT[BM];

    const int s = blockIdx.x;
    if (s >= *nsegR) return;
    const int isf32 = *flag;
    const int tid = threadIdx.x;
    const int2 sd = segdesc[s];
    const int e = sd.x, slot0 = sd.y;
    const int n0 = blockIdx.y * 64;
    const unsigned short* W2 = w2t + (size_t)e * D_DIM * H_DIM;

    if (tid < BM) lT[tid] = toklist[slot0 + tid];
    __syncthreads();

    floatx4 acc[4][2];
#pragma unroll
    for (int fm = 0; fm < 4; fm++)
#pragma unroll
        for (int fn = 0; fn < 2; fn++) { floatx4 zz = {0.f,0.f,0.f,0.f}; acc[fm][fn] = zz; }
    const int wave = tid >> 6, lane = tid & 63;
    const int wm = (wave >> 1) * 64, wn = (wave & 1) * 32;
    const int lm = lane & 15, lq = lane >> 4;

    for (int k0 = 0; k0 < H_DIM; k0 += BK) {
#pragma unroll
        for (int i = 0; i < 4; i++) {
            int m = (tid >> 3) + i * 32, kv = (tid & 7) * 8;
            *(uint4v*)&lA[m][kv] = *(const uint4v*)(Abuf + (size_t)(slot0 + m) * H_DIM + k0 + kv);
        }
#pragma unroll
        for (int i = 0; i < 2; i++) {
            int n = (tid >> 3) + i * 32, kc = (tid & 7) * 8;
            *(uint4v*)&lB[n][kc] = *(const uint4v*)(W2 + (size_t)(n0 + n) * H_DIM + k0 + kc);
        }
        __syncthreads();
#pragma unroll
        for (int kk = 0; kk < BK; kk += 32) {
            short8 af[4], bf[2];
#pragma unroll
            for (int fm = 0; fm < 4; fm++) af[fm] = *(const short8*)&lA[wm + fm * 16 + lm][kk + lq * 8];
#pragma unroll
            for (int fn = 0; fn < 2; fn++) bf[fn] = *(const short8*)&lB[wn + fn * 16 + lm][kk + lq * 8];
#pragma unroll
            for (int fm = 0; fm < 4; fm++)
#pragma unroll
                for (int fn = 0; fn < 2; fn++)
                    acc[fm][fn] = __builtin_amdgcn_mfma_f32_16x16x32_bf16(af[fm], bf[fn], acc[fm][fn], 0, 0, 0);
        }
        __syncthreads();
    }
#pragma unroll
    for (int fm = 0; fm < 4; fm++)
#pragma unroll
        for (int r = 0; r < 4; r++) {
            int row = wm + fm * 16 + lq * 4 + r;
            int t = lT[row];
#pragma unroll
            for (int fn = 0; fn < 2; fn++) {
                int col = wn + fn * 16 + lm;
                float val = acc[fm][fn][r];
                if (isf32) atomicAdd((float*)out_ + (size_t)t * D_DIM + n0 + col, val);
                else       atomAddBf16((unsigned short*)out_ + (size_t)t * D_DIM + n0 + col, val);
            }
        }
}

// ---------------------------------------------------------------------------
extern "C" void kernel_launch(void* const* d_in, const int* in_sizes, int n_in,
                              void* d_out, int out_size, void* d_ws, size_t ws_size,
                              hipStream_t stream)
{
    const void* x   = d_in[0];
    const void* rw  = d_in[1];
    const void* rb  = d_in[2];
    const void* rw1 = d_in[3];
    const void* rw3 = d_in[4];
    const void* rw2 = d_in[5];
    const void* sw1 = d_in[6];
    const void* sw3 = d_in[7];
    const void* sw2 = d_in[8];

    const int T = in_sizes[0] / D_DIM;          // 4096
    const int SLOT_MAX = 2 * T + NEXP * BM;     // 9216
    const int MAXSEGR  = SLOT_MAX / BM;         // 72
    const int MAXSEGH  = MAXSEGR + 2 * (T / BM);// 136

    char* p = (char*)d_ws;
    int*    flag     = (int*)p;
    int*    nsegR    = (int*)(p + 64);
    int*    nsegAll  = (int*)(p + 96);
    int*    fill     = (int*)(p + 128);         // 8 x 16 ints (64B padded)
    int2*   segdesc  = (int2*)(p + 1024);       // up to 136 segs
    size_t  o = 4096;
    int*    topkE    = (int*)(p + o);    o += (size_t)4 * T;
    float2* topkG    = (float2*)(p + o); o += (size_t)8 * T;
    int2*   slotof   = (int2*)(p + o);   o += (size_t)8 * T;
    int*    toklist  = (int*)(p + o);    o += (size_t)4 * SLOT_MAX;
    float*  slotgate = (float*)(p + o);  o += (size_t)4 * SLOT_MAX;
    o = (o + 255) & ~(size_t)255;
    // layout: w1t | AbufSh | AbufRt | w3t | xb   (w3t+xb reused as Or; w1t as w2t)
    unsigned short* w1t    = (unsigned short*)(p + o); o += (size_t)NP * H_DIM * D_DIM * 2;
    unsigned short* AbufSh = (unsigned short*)(p + o); o += (size_t)T * (2 * H_DIM) * 2;
    unsigned short* AbufRt = (unsigned short*)(p + o); o += (size_t)SLOT_MAX * H_DIM * 2;
    unsigned short* w3t    = (unsigned short*)(p + o); o += (size_t)NP * H_DIM * D_DIM * 2;
    unsigned short* xb     = (unsigned short*)(p + o);
    const size_t REQ = o + (size_t)T * D_DIM * 2;   // ~47.35 MB
    const int fast = (ws_size >= REQ) ? 1 : 0;
    unsigned short* w2t = w1t;   // overlay: w1t dead after h_all
    unsigned short* Or  = w3t;   // overlay: w3t+xb (18.87MB) dead after h_all

    detect_kernel<<<1, 256, 0, stream>>>((const unsigned short*)x, flag);
    transp13_kernel<<<dim3(D_DIM / 32, H_DIM / 64, 2 * NP), 256, 0, stream>>>(
        rw1, rw3, sw1, sw3, w1t, w3t, flag);
    router_kernel<<<T / 4, 256, 0, stream>>>(x, rw, rb, flag, topkE, topkG, xb, fast, T);
    segcnt_kernel<<<1, 256, 0, stream>>>(topkE, T, fill, segdesc, nsegR, nsegAll, toklist, slotgate);
    gather_kernel<<<(T + 255) / 256, 256, 0, stream>>>(topkE, topkG, fill, toklist, slotgate, slotof, T);
    moe_h_all_kernel<<<dim3(MAXSEGH, H_DIM / 64), 256, 0, stream>>>(
        x, xb, w1t, w3t, flag, fast, toklist, slotgate, segdesc, nsegAll, AbufSh, AbufRt);
    transp_kernel<<<dim3(H_DIM / 32, D_DIM / 64, NP), 256, 0, stream>>>(rw2, sw2, w2t, H_DIM, D_DIM, flag);
    if (fast) {
        moe_out_routed_or_kernel<<<dim3(MAXSEGR, D_DIM / 128), 256, 0, stream>>>(
            AbufRt, w2t, segdesc, nsegR, Or);
        moe_out_shared_kernel<<<dim3(T / BM, D_DIM / 128), 256, 0, stream>>>(
            AbufSh, w2t, flag, 1, Or, slotof, d_out);
    } else {
        moe_out_shared_kernel<<<dim3(T / BM, D_DIM / 128), 256, 0, stream>>>(
            AbufSh, w2t, flag, 0, nullptr, nullptr, d_out);
        moe_out_routed_atomic_kernel<<<dim3(MAXSEGR, D_DIM / 64), 256, 0, stream>>>(
            AbufRt, w2t, segdesc, nsegR, toklist, flag, d_out);
    }
}

// Round 9
// 273.236 us; speedup vs baseline: 1.2482x; 1.0191x over previous
//
#include <hip/hip_runtime.h>
#include <stdint.h>

#define D_DIM 1024
#define H_DIM 512
#define NEXP  8
#define NP    10            // 8 routed + 2 shared expert passes

#define BM 128
#define BK 64
#define LDK 72              // padded stride (fallback atomic kernel only)

typedef __attribute__((ext_vector_type(8))) short short8;     // 8 bf16 MFMA operand
typedef __attribute__((ext_vector_type(4))) float floatx4;    // MFMA accumulator
typedef __attribute__((ext_vector_type(4))) unsigned int uint4v;
typedef __attribute__((ext_vector_type(4))) float float4v;

typedef __attribute__((address_space(3))) unsigned char* as3p;
typedef const __attribute__((address_space(1))) unsigned char* as1p;

__device__ __forceinline__ void async16(void* lds, const void* g) {
    // wave-uniform LDS base; HW scatters lane i -> lds + i*16
    __builtin_amdgcn_global_load_lds((as1p)g, (as3p)lds, 16, 0, 0);
}

__device__ __forceinline__ float bf2f(unsigned short u) {
    union { float f; unsigned int i; } v; v.i = ((unsigned int)u) << 16; return v.f;
}
__device__ __forceinline__ unsigned short f2bf(float f) {
    union { float f; unsigned int i; } v; v.f = f;
    unsigned int r = v.i + 0x7FFFu + ((v.i >> 16) & 1u);   // RNE
    return (unsigned short)(r >> 16);
}

// bf16 atomic add via CAS (fallback path only)
__device__ void atomAddBf16(unsigned short* pp, float v) {
    unsigned int* w = (unsigned int*)((size_t)pp & ~(size_t)3);
    const bool hi = ((size_t)pp & 2) != 0;
    unsigned int old = *w, assumed;
    do {
        assumed = old;
        unsigned short cur = hi ? (unsigned short)(assumed >> 16)
                                : (unsigned short)(assumed & 0xFFFFu);
        unsigned short nv = f2bf(bf2f(cur) + v);
        unsigned int repl = hi ? ((assumed & 0x0000FFFFu) | ((unsigned)nv << 16))
                               : ((assumed & 0xFFFF0000u) | nv);
        old = atomicCAS(w, assumed, repl);
    } while (old != assumed);
}

// ---------------------------------------------------------------------------
__global__ void detect_kernel(const unsigned short* __restrict__ x, int* flag)
{
    __shared__ int bad;
    if (threadIdx.x == 0) bad = 0;
    __syncthreads();
    int b = 0;
    for (int i = threadIdx.x; i < 8192; i += 256) {
        int e = (x[i] >> 7) & 0xFF;
        if (e >= 0xA0) b = 1;
    }
    if (b) atomicOr(&bad, 1);
    __syncthreads();
    if (threadIdx.x == 0) *flag = bad;
}

// ---------------------------------------------------------------------------
// w1 + w3 transpose+convert: z 0..9 -> w1t, z 10..19 -> w3t  ([K][N]->[N][K])
// ---------------------------------------------------------------------------
__global__ __launch_bounds__(256) void transp13_kernel(
    const void* __restrict__ rw1, const void* __restrict__ rw3,
    const void* __restrict__ sw1, const void* __restrict__ sw3,
    unsigned short* __restrict__ w1t, unsigned short* __restrict__ w3t,
    const int* __restrict__ flag)
{
    const int isf32 = *flag;
    const int z = blockIdx.z;
    const int grp = z / 10, zz = z % 10;
    const void* src_ = grp == 0 ? (zz < 8 ? rw1 : sw1) : (zz < 8 ? rw3 : sw3);
    unsigned short* dstB = grp == 0 ? w1t : w3t;
    const size_t moff = (size_t)(zz < 8 ? zz : zz - 8) * D_DIM * H_DIM;
    const int nl = threadIdx.x & 63, j = threadIdx.x >> 6;
    const int n = blockIdx.y * 64 + nl;
    const int k0 = blockIdx.x * 32 + j * 8;

    unsigned short v[8];
    if (isf32) {
        const float* src = (const float*)src_ + moff;
#pragma unroll
        for (int j2 = 0; j2 < 8; j2++) v[j2] = f2bf(src[(size_t)(k0 + j2) * H_DIM + n]);
    } else {
        const unsigned short* src = (const unsigned short*)src_ + moff;
#pragma unroll
        for (int j2 = 0; j2 < 8; j2++) v[j2] = src[(size_t)(k0 + j2) * H_DIM + n];
    }
    uint4v w;
#pragma unroll
    for (int q = 0; q < 4; q++) w[q] = (unsigned)v[2 * q] | ((unsigned)v[2 * q + 1] << 16);
    *(uint4v*)(dstB + ((size_t)zz * H_DIM + n) * D_DIM + k0) = w;
}

// ---------------------------------------------------------------------------
// Generic transpose (w2): src [nmat][K][N] -> dst bf16 [nmat][N][K]
// ---------------------------------------------------------------------------
__global__ __launch_bounds__(256) void transp_kernel(
    const void* __restrict__ rsrc, const void* __restrict__ ssrc,
    unsigned short* __restrict__ dst, int K, int N, const int* __restrict__ flag)
{
    const int isf32 = *flag;
    const int z = blockIdx.z;
    const size_t moff = (size_t)(z < 8 ? z : z - 8) * K * N;
    const int nl = threadIdx.x & 63, j = threadIdx.x >> 6;
    const int n = blockIdx.y * 64 + nl;
    const int k0 = blockIdx.x * 32 + j * 8;

    unsigned short v[8];
    if (isf32) {
        const float* src = (const float*)(z < 8 ? rsrc : ssrc) + moff;
#pragma unroll
        for (int j2 = 0; j2 < 8; j2++) v[j2] = f2bf(src[(size_t)(k0 + j2) * N + n]);
    } else {
        const unsigned short* src = (const unsigned short*)(z < 8 ? rsrc : ssrc) + moff;
#pragma unroll
        for (int j2 = 0; j2 < 8; j2++) v[j2] = src[(size_t)(k0 + j2) * N + n];
    }
    uint4v w;
#pragma unroll
    for (int q = 0; q < 4; q++) w[q] = (unsigned)v[2 * q] | ((unsigned)v[2 * q + 1] << 16);
    *(uint4v*)(dst + ((size_t)z * N + n) * K + k0) = w;
}

// ---------------------------------------------------------------------------
// Router: one wave per token -> top-2 ids + gates; fp32 mode also emits bf16 xb.
// ---------------------------------------------------------------------------
__global__ __launch_bounds__(256, 4) void router_kernel(
    const void* __restrict__ xv_, const void* __restrict__ rwv_,
    const void* __restrict__ rbv_, const int* __restrict__ flag,
    int* __restrict__ topkE, float2* __restrict__ topkG,
    unsigned short* __restrict__ xb, int useXb, int T)
{
    const int isf32 = *flag;
    int gid  = blockIdx.x * blockDim.x + threadIdx.x;
    int t    = gid >> 6;
    int lane = threadIdx.x & 63;
    if (t >= T) return;

    float acc[NEXP];
#pragma unroll
    for (int e = 0; e < NEXP; e++) acc[e] = 0.f;

    if (isf32) {
        const float* xr = (const float*)xv_ + (size_t)t * D_DIM;
        const float* rw = (const float*)rwv_;
        unsigned short* xo = xb + (size_t)t * D_DIM;
#pragma unroll 4
        for (int i = 0; i < D_DIM / 64; i++) {
            int d = i * 64 + lane;
            float xv = xr[d];
            if (useXb) xo[d] = f2bf(xv);
            float4v wa = *(const float4v*)(rw + (size_t)d * NEXP);
            float4v wb = *(const float4v*)(rw + (size_t)d * NEXP + 4);
#pragma unroll
            for (int q = 0; q < 4; q++) { acc[q] += xv * wa[q]; acc[q + 4] += xv * wb[q]; }
        }
    } else {
        const unsigned short* xr = (const unsigned short*)xv_ + (size_t)t * D_DIM;
        const unsigned short* rw = (const unsigned short*)rwv_;
#pragma unroll 4
        for (int i = 0; i < D_DIM / 64; i++) {
            int d = i * 64 + lane;
            float xv = bf2f(xr[d]);
            uint4v wv = *(const uint4v*)(rw + (size_t)d * NEXP);
#pragma unroll
            for (int q = 0; q < 4; q++) {
                unsigned int w = wv[q];
                acc[q * 2 + 0] += xv * bf2f((unsigned short)(w & 0xFFFFu));
                acc[q * 2 + 1] += xv * bf2f((unsigned short)(w >> 16));
            }
        }
    }
#pragma unroll
    for (int m = 32; m >= 1; m >>= 1) {
#pragma unroll
        for (int e = 0; e < NEXP; e++) acc[e] += __shfl_xor(acc[e], m, 64);
    }
    if (lane == 0) {
#pragma unroll
        for (int e = 0; e < NEXP; e++)
            acc[e] += isf32 ? ((const float*)rbv_)[e] : bf2f(((const unsigned short*)rbv_)[e]);
        int i1 = 0; float v1 = acc[0];
#pragma unroll
        for (int e = 1; e < NEXP; e++) if (acc[e] > v1) { v1 = acc[e]; i1 = e; }
        int i2 = -1; float v2 = -3.4e38f;
#pragma unroll
        for (int e = 0; e < NEXP; e++) if (e != i1 && acc[e] > v2) { v2 = acc[e]; i2 = e; }
        float g1 = 1.f / (1.f + __expf(v2 - v1));
        float g2 = 1.f - g1;
        topkE[t] = i1 | (i2 << 8);
        float2 g; g.x = g1; g.y = g2;
        topkG[t] = g;
    }
}

// ---------------------------------------------------------------------------
// segcnt: 256 threads, LDS-reduced histogram, padded routed segments + shared
// segments, pad-slot zeroing, 64B-padded fill bases.
// ---------------------------------------------------------------------------
__global__ __launch_bounds__(256) void segcnt_kernel(
    const int* __restrict__ topkE, int T,
    int* __restrict__ fill, int2* __restrict__ segdesc,
    int* __restrict__ nsegR, int* __restrict__ nsegAll,
    int* __restrict__ toklist, float* __restrict__ slotgate)
{
    __shared__ int hist[NEXP];
    const int tid = threadIdx.x;
    if (tid < NEXP) hist[tid] = 0;
    __syncthreads();
    int c[NEXP];
#pragma unroll
    for (int e = 0; e < NEXP; e++) c[e] = 0;
    for (int i = tid; i < T; i += 256) {
        int pk = topkE[i];
        int e0 = pk & 255, e1 = pk >> 8;
#pragma unroll
        for (int e = 0; e < NEXP; e++) c[e] += (e0 == e) + (e1 == e);
    }
#pragma unroll
    for (int m = 32; m >= 1; m >>= 1) {
#pragma unroll
        for (int e = 0; e < NEXP; e++) c[e] += __shfl_xor(c[e], m, 64);
    }
    if ((tid & 63) == 0) {
#pragma unroll
        for (int e = 0; e < NEXP; e++) atomicAdd(&hist[e], c[e]);
    }
    __syncthreads();
    int base[NEXP + 1];
    base[0] = 0;
#pragma unroll
    for (int e = 0; e < NEXP; e++) {
        int nsg = (hist[e] + BM - 1) / BM;
        base[e + 1] = base[e] + nsg * BM;
    }
    if (tid == 0) {
        int ns = 0;
        for (int e = 0; e < NEXP; e++)
            for (int b = base[e]; b < base[e + 1]; b += BM) {
                int2 s; s.x = e; s.y = b; segdesc[ns++] = s;
            }
        *nsegR = ns;
        for (int z = 0; z < 2; z++)
            for (int t0 = 0; t0 < T; t0 += BM) {
                int2 s; s.x = 8 + z; s.y = t0; segdesc[ns++] = s;
            }
        *nsegAll = ns;
    }
    if (tid < NEXP) fill[tid * 16] = base[tid];
    for (int e = 0; e < NEXP; e++)
        for (int i = base[e] + hist[e] + tid; i < base[e + 1]; i += 256) {
            toklist[i] = 0; slotgate[i] = 0.f;
        }
}

// ---------------------------------------------------------------------------
// gather: hierarchical slot assignment; records slotof per token.
// ---------------------------------------------------------------------------
__global__ __launch_bounds__(256) void gather_kernel(
    const int* __restrict__ topkE, const float2* __restrict__ topkG,
    int* __restrict__ fill, int* __restrict__ toklist,
    float* __restrict__ slotgate, int2* __restrict__ slotof, int T)
{
    __shared__ int hist[NEXP], sbase[NEXP], rank[NEXP];
    const int tid = threadIdx.x;
    if (tid < NEXP) { hist[tid] = 0; rank[tid] = 0; }
    __syncthreads();
    const int t = blockIdx.x * 256 + tid;
    int e0 = 0, e1 = 0; float2 g; g.x = 0.f; g.y = 0.f;
    const bool valid = (t < T);
    if (valid) {
        int pk = topkE[t]; g = topkG[t];
        e0 = pk & 255; e1 = pk >> 8;
        atomicAdd(&hist[e0], 1);
        atomicAdd(&hist[e1], 1);
    }
    __syncthreads();
    if (tid < NEXP) sbase[tid] = atomicAdd(&fill[tid * 16], hist[tid]);
    __syncthreads();
    if (valid) {
        int s0 = sbase[e0] + atomicAdd(&rank[e0], 1);
        int s1 = sbase[e1] + atomicAdd(&rank[e1], 1);
        toklist[s0] = t; slotgate[s0] = g.x;
        toklist[s1] = t; slotgate[s1] = g.y;
        int2 so; so.x = s0; so.y = s1;
        slotof[t] = so;
    }
}

// ---------------------------------------------------------------------------
// Unified hidden: 128x64 tile, dual acc, global_load_lds + XOR-swizzled LDS.
// LDS row = 64 elems (128B, no pad). Granule g of row r stored at pos g^(r&7).
// grid (MAXSEGH, H/64 = 8)
// ---------------------------------------------------------------------------
__global__ __launch_bounds__(256, 4) void moe_h_all_kernel(
    const void* __restrict__ x_, const unsigned short* __restrict__ xb,
    const unsigned short* __restrict__ w1t, const unsigned short* __restrict__ w3t,
    const int* __restrict__ flag, int useXb,
    const int* __restrict__ toklist, const float* __restrict__ slotgate,
    const int2* __restrict__ segdesc, const int* __restrict__ nsegAll,
    unsigned short* __restrict__ AbufSh, unsigned short* __restrict__ AbufRt)
{
    __shared__ __align__(16) unsigned short lA[BM][64];
    __shared__ __align__(16) unsigned short lB1[64][64];
    __shared__ __align__(16) unsigned short lB3[64][64];
    __shared__ int   lT[BM];
    __shared__ float lG[BM];

    const int s = blockIdx.x;
    if (s >= *nsegAll) return;
    const int tid = threadIdx.x;
    const int2 sd = segdesc[s];
    const int e = sd.x, slot0 = sd.y;
    const int n0 = blockIdx.y * 64;
    const unsigned short* W1 = w1t + (size_t)e * H_DIM * D_DIM;
    const unsigned short* W3 = w3t + (size_t)e * H_DIM * D_DIM;

    if (tid < BM) {
        if (e < 8) { lT[tid] = toklist[slot0 + tid]; lG[tid] = slotgate[slot0 + tid]; }
        else       { lT[tid] = slot0 + tid;          lG[tid] = 1.f; }
    }
    __syncthreads();

    const int wave = tid >> 6, lane = tid & 63;
    const int wm = (wave >> 1) * 64, wn = (wave & 1) * 32;
    const int lm = lane & 15, lq = lane >> 4;
    const int sw = (lane & 7) ^ ((lane >> 3) & 7);   // source granule for my slot

    const int isf32 = *flag;
    const unsigned short* xs = (isf32 && useXb) ? xb : (const unsigned short*)x_;
    const bool conv = (isf32 && !useXb);

    const unsigned short* aSrc[4];
    const unsigned short* b1Src[2];
    const unsigned short* b3Src[2];
    if (!conv) {
#pragma unroll
        for (int j = 0; j < 4; j++) {
            int r = (4 * wave + j) * 8 + (lane >> 3);
            aSrc[j] = xs + (size_t)lT[r] * D_DIM + sw * 8;
        }
    }
#pragma unroll
    for (int j = 0; j < 2; j++) {
        int r = (2 * wave + j) * 8 + (lane >> 3);
        b1Src[j] = W1 + (size_t)(n0 + r) * D_DIM + sw * 8;
        b3Src[j] = W3 + (size_t)(n0 + r) * D_DIM + sw * 8;
    }
    unsigned short* lAf  = &lA[0][0];
    unsigned short* lB1f = &lB1[0][0];
    unsigned short* lB3f = &lB3[0][0];

    floatx4 acc1[4][2], acc3[4][2];
#pragma unroll
    for (int fm = 0; fm < 4; fm++)
#pragma unroll
        for (int fn = 0; fn < 2; fn++) {
            floatx4 zz = {0.f, 0.f, 0.f, 0.f};
            acc1[fm][fn] = zz; acc3[fm][fn] = zz;
        }

    for (int k0 = 0; k0 < D_DIM; k0 += BK) {
        if (!conv) {
#pragma unroll
            for (int j = 0; j < 4; j++)
                async16(lAf + (4 * wave + j) * 512, aSrc[j] + k0);
        } else {
            const float* xf = (const float*)x_;
#pragma unroll
            for (int i = 0; i < 4; i++) {
                int m = (tid >> 3) + i * 32, pos = (tid & 7);
                int gsrc = pos ^ (m & 7);
                const float* src = xf + (size_t)lT[m] * D_DIM + k0 + gsrc * 8;
                float4v a = *(const float4v*)src, b = *(const float4v*)(src + 4);
                uint4v v;
#pragma unroll
                for (int q = 0; q < 2; q++) {
                    v[q]     = (unsigned)f2bf(a[2 * q]) | ((unsigned)f2bf(a[2 * q + 1]) << 16);
                    v[q + 2] = (unsigned)f2bf(b[2 * q]) | ((unsigned)f2bf(b[2 * q + 1]) << 16);
                }
                *(uint4v*)&lA[m][pos * 8] = v;
            }
        }
#pragma unroll
        for (int j = 0; j < 2; j++) {
            async16(lB1f + (2 * wave + j) * 512, b1Src[j] + k0);
            async16(lB3f + (2 * wave + j) * 512, b3Src[j] + k0);
        }
        __syncthreads();
#pragma unroll
        for (int kk = 0; kk < BK; kk += 32) {
            const int p8 = (((kk >> 3) + lq) ^ (lm & 7)) * 8;
            short8 af[4], b1f[2], b3f[2];
#pragma unroll
            for (int fm = 0; fm < 4; fm++)
                af[fm] = *(const short8*)&lA[wm + fm * 16 + lm][p8];
#pragma unroll
            for (int fn = 0; fn < 2; fn++) {
                b1f[fn] = *(const short8*)&lB1[wn + fn * 16 + lm][p8];
                b3f[fn] = *(const short8*)&lB3[wn + fn * 16 + lm][p8];
            }
#pragma unroll
            for (int fm = 0; fm < 4; fm++)
#pragma unroll
                for (int fn = 0; fn < 2; fn++) {
                    acc1[fm][fn] = __builtin_amdgcn_mfma_f32_16x16x32_bf16(af[fm], b1f[fn], acc1[fm][fn], 0, 0, 0);
                    acc3[fm][fn] = __builtin_amdgcn_mfma_f32_16x16x32_bf16(af[fm], b3f[fn], acc3[fm][fn], 0, 0, 0);
                }
        }
        __syncthreads();
    }
#pragma unroll
    for (int fm = 0; fm < 4; fm++)
#pragma unroll
        for (int r = 0; r < 4; r++) {
            int row = wm + fm * 16 + lq * 4 + r;
            float g = lG[row];
#pragma unroll
            for (int fn = 0; fn < 2; fn++) {
                float a1 = acc1[fm][fn][r], a3 = acc3[fm][fn][r];
                float h = a1 / (1.f + __expf(-a1)) * a3 * g;
                int col = wn + fn * 16 + lm;
                if (e < 8)
                    AbufRt[(size_t)(slot0 + row) * H_DIM + n0 + col] = f2bf(h);
                else
                    AbufSh[(size_t)(slot0 + row) * (2 * H_DIM) + (e - 8) * H_DIM + n0 + col] = f2bf(h);
            }
        }
}

// ---------------------------------------------------------------------------
// Routed out: Or[slot,1024] = AbufRt[slot,512] @ w2_e. 128x64 tile, async +
// swizzle, high grid parallelism. grid (MAXSEGR, D/64 = 16)
// ---------------------------------------------------------------------------
__global__ __launch_bounds__(256, 4) void moe_out_routed_or_kernel(
    const unsigned short* __restrict__ Abuf, const unsigned short* __restrict__ w2t,
    const int2* __restrict__ segdesc, const int* __restrict__ nsegR,
    unsigned short* __restrict__ Or)
{
    __shared__ __align__(16) unsigned short lA[BM][64];
    __shared__ __align__(16) unsigned short lB[64][64];

    const int s = blockIdx.x;
    if (s >= *nsegR) return;
    const int tid = threadIdx.x;
    const int2 sd = segdesc[s];
    const int e = sd.x, slot0 = sd.y;
    const int n0 = blockIdx.y * 64;
    const unsigned short* W2 = w2t + (size_t)e * D_DIM * H_DIM;

    const int wave = tid >> 6, lane = tid & 63;
    const int wm = (wave >> 1) * 64, wn = (wave & 1) * 32;
    const int lm = lane & 15, lq = lane >> 4;
    const int sw = (lane & 7) ^ ((lane >> 3) & 7);

    const unsigned short* aSrc[4];
    const unsigned short* bSrc[2];
#pragma unroll
    for (int j = 0; j < 4; j++) {
        int r = (4 * wave + j) * 8 + (lane >> 3);
        aSrc[j] = Abuf + (size_t)(slot0 + r) * H_DIM + sw * 8;
    }
#pragma unroll
    for (int j = 0; j < 2; j++) {
        int r = (2 * wave + j) * 8 + (lane >> 3);
        bSrc[j] = W2 + (size_t)(n0 + r) * H_DIM + sw * 8;
    }
    unsigned short* lAf = &lA[0][0];
    unsigned short* lBf = &lB[0][0];

    floatx4 acc[4][2];
#pragma unroll
    for (int fm = 0; fm < 4; fm++)
#pragma unroll
        for (int fn = 0; fn < 2; fn++) { floatx4 zz = {0.f,0.f,0.f,0.f}; acc[fm][fn] = zz; }

    for (int k0 = 0; k0 < H_DIM; k0 += BK) {
#pragma unroll
        for (int j = 0; j < 4; j++)
            async16(lAf + (4 * wave + j) * 512, aSrc[j] + k0);
#pragma unroll
        for (int j = 0; j < 2; j++)
            async16(lBf + (2 * wave + j) * 512, bSrc[j] + k0);
        __syncthreads();
#pragma unroll
        for (int kk = 0; kk < BK; kk += 32) {
            const int p8 = (((kk >> 3) + lq) ^ (lm & 7)) * 8;
            short8 af[4], bf[2];
#pragma unroll
            for (int fm = 0; fm < 4; fm++) af[fm] = *(const short8*)&lA[wm + fm * 16 + lm][p8];
#pragma unroll
            for (int fn = 0; fn < 2; fn++) bf[fn] = *(const short8*)&lB[wn + fn * 16 + lm][p8];
#pragma unroll
            for (int fm = 0; fm < 4; fm++)
#pragma unroll
                for (int fn = 0; fn < 2; fn++)
                    acc[fm][fn] = __builtin_amdgcn_mfma_f32_16x16x32_bf16(af[fm], bf[fn], acc[fm][fn], 0, 0, 0);
        }
        __syncthreads();
    }
#pragma unroll
    for (int fm = 0; fm < 4; fm++)
#pragma unroll
        for (int r = 0; r < 4; r++) {
            int row = wm + fm * 16 + lq * 4 + r;
#pragma unroll
            for (int fn = 0; fn < 2; fn++) {
                int col = wn + fn * 16 + lm;
                Or[(size_t)(slot0 + row) * D_DIM + n0 + col] = f2bf(acc[fm][fn][r]);
            }
        }
}

// ---------------------------------------------------------------------------
// Shared out (+fused routed combine): out[t] = AbufSh[t]@sw2cat + Or[s0]+Or[s1]
// 128x64 tile, async + swizzle. grid (T/128, D/64 = 16)
// ---------------------------------------------------------------------------
__global__ __launch_bounds__(256, 4) void moe_out_shared_kernel(
    const unsigned short* __restrict__ Abuf, const unsigned short* __restrict__ w2t,
    const int* __restrict__ flag, int fused,
    const unsigned short* __restrict__ Or, const int2* __restrict__ slotof,
    void* __restrict__ out_)
{
    __shared__ __align__(16) unsigned short lA[BM][64];
    __shared__ __align__(16) unsigned short lB[64][64];
    __shared__ int2 lS[BM];

    const int isf32 = *flag;
    const int tid = threadIdx.x;
    const int t0 = blockIdx.x * BM, n0 = blockIdx.y * 64;

    if (fused && tid < BM) lS[tid] = slotof[t0 + tid];
    __syncthreads();

    const int wave = tid >> 6, lane = tid & 63;
    const int wm = (wave >> 1) * 64, wn = (wave & 1) * 32;
    const int lm = lane & 15, lq = lane >> 4;
    const int sw = (lane & 7) ^ ((lane >> 3) & 7);

    const unsigned short* aSrc[4];
    size_t bRow[2];
#pragma unroll
    for (int j = 0; j < 4; j++) {
        int r = (4 * wave + j) * 8 + (lane >> 3);
        aSrc[j] = Abuf + (size_t)(t0 + r) * (2 * H_DIM) + sw * 8;
    }
#pragma unroll
    for (int j = 0; j < 2; j++) {
        int r = (2 * wave + j) * 8 + (lane >> 3);
        bRow[j] = (size_t)(n0 + r) * H_DIM + sw * 8;
    }
    unsigned short* lAf = &lA[0][0];
    unsigned short* lBf = &lB[0][0];

    floatx4 acc[4][2];
#pragma unroll
    for (int fm = 0; fm < 4; fm++)
#pragma unroll
        for (int fn = 0; fn < 2; fn++) { floatx4 zz = {0.f,0.f,0.f,0.f}; acc[fm][fn] = zz; }

    for (int k0 = 0; k0 < 2 * H_DIM; k0 += BK) {
        const unsigned short* W2 = w2t + (size_t)(8 + (k0 >> 9)) * D_DIM * H_DIM;
        const int kk0 = k0 & (H_DIM - 1);
#pragma unroll
        for (int j = 0; j < 4; j++)
            async16(lAf + (4 * wave + j) * 512, aSrc[j] + k0);
#pragma unroll
        for (int j = 0; j < 2; j++)
            async16(lBf + (2 * wave + j) * 512, W2 + bRow[j] + kk0);
        __syncthreads();
#pragma unroll
        for (int kk = 0; kk < BK; kk += 32) {
            const int p8 = (((kk >> 3) + lq) ^ (lm & 7)) * 8;
            short8 af[4], bf[2];
#pragma unroll
            for (int fm = 0; fm < 4; fm++) af[fm] = *(const short8*)&lA[wm + fm * 16 + lm][p8];
#pragma unroll
            for (int fn = 0; fn < 2; fn++) bf[fn] = *(const short8*)&lB[wn + fn * 16 + lm][p8];
#pragma unroll
            for (int fm = 0; fm < 4; fm++)
#pragma unroll
                for (int fn = 0; fn < 2; fn++)
                    acc[fm][fn] = __builtin_amdgcn_mfma_f32_16x16x32_bf16(af[fm], bf[fn], acc[fm][fn], 0, 0, 0);
        }
        __syncthreads();
    }
#pragma unroll
    for (int fm = 0; fm < 4; fm++)
#pragma unroll
        for (int r = 0; r < 4; r++) {
            int row = wm + fm * 16 + lq * 4 + r;
            int2 so; so.x = 0; so.y = 0;
            if (fused) so = lS[row];
#pragma unroll
            for (int fn = 0; fn < 2; fn++) {
                int col = wn + fn * 16 + lm;
                float val = acc[fm][fn][r];
                if (fused) {
                    val += bf2f(Or[(size_t)so.x * D_DIM + n0 + col]);
                    val += bf2f(Or[(size_t)so.y * D_DIM + n0 + col]);
                }
                size_t off = (size_t)(t0 + row) * D_DIM + n0 + col;
                if (isf32) ((float*)out_)[off] = val;
                else       ((unsigned short*)out_)[off] = f2bf(val);
            }
        }
}

// ---------------------------------------------------------------------------
// Routed out fallback (ws too small): atomic scatter, padded-LDS staging.
// ---------------------------------------------------------------------------
__global__ __launch_bounds__(256, 3) void moe_out_routed_atomic_kernel(
    const unsigned short* __restrict__ Abuf, const unsigned short* __restrict__ w2t,
    const int2* __restrict__ segdesc, const int* __restrict__ nsegR,
    const int* __restrict__ toklist, const int* __restrict__ flag,
    void* __restrict__ out_)
{
    __shared__ __align__(16) unsigned short lA[BM][LDK];
    __shared__ __align__(16) unsigned short lB[64][LDK];
    __shared__ int lT[BM];

    const int s = blockIdx.x;
    if (s >= *nsegR) return;
    const int isf32 = *flag;
    const int tid = threadIdx.x;
    const int2 sd = segdesc[s];
    const int e = sd.x, slot0 = sd.y;
    const int n0 = blockIdx.y * 64;
    const unsigned short* W2 = w2t + (size_t)e * D_DIM * H_DIM;

    if (tid < BM) lT[tid] = toklist[slot0 + tid];
    __syncthreads();

    floatx4 acc[4][2];
#pragma unroll
    for (int fm = 0; fm < 4; fm++)
#pragma unroll
        for (int fn = 0; fn < 2; fn++) { floatx4 zz = {0.f,0.f,0.f,0.f}; acc[fm][fn] = zz; }
    const int wave = tid >> 6, lane = tid & 63;
    const int wm = (wave >> 1) * 64, wn = (wave & 1) * 32;
    const int lm = lane & 15, lq = lane >> 4;

    for (int k0 = 0; k0 < H_DIM; k0 += BK) {
#pragma unroll
        for (int i = 0; i < 4; i++) {
            int m = (tid >> 3) + i * 32, kv = (tid & 7) * 8;
            *(uint4v*)&lA[m][kv] = *(const uint4v*)(Abuf + (size_t)(slot0 + m) * H_DIM + k0 + kv);
        }
#pragma unroll
        for (int i = 0; i < 2; i++) {
            int n = (tid >> 3) + i * 32, kc = (tid & 7) * 8;
            *(uint4v*)&lB[n][kc] = *(const uint4v*)(W2 + (size_t)(n0 + n) * H_DIM + k0 + kc);
        }
        __syncthreads();
#pragma unroll
        for (int kk = 0; kk < BK; kk += 32) {
            short8 af[4], bf[2];
#pragma unroll
            for (int fm = 0; fm < 4; fm++) af[fm] = *(const short8*)&lA[wm + fm * 16 + lm][kk + lq * 8];
#pragma unroll
            for (int fn = 0; fn < 2; fn++) bf[fn] = *(const short8*)&lB[wn + fn * 16 + lm][kk + lq * 8];
#pragma unroll
            for (int fm = 0; fm < 4; fm++)
#pragma unroll
                for (int fn = 0; fn < 2; fn++)
                    acc[fm][fn] = __builtin_amdgcn_mfma_f32_16x16x32_bf16(af[fm], bf[fn], acc[fm][fn], 0, 0, 0);
        }
        __syncthreads();
    }
#pragma unroll
    for (int fm = 0; fm < 4; fm++)
#pragma unroll
        for (int r = 0; r < 4; r++) {
            int row = wm + fm * 16 + lq * 4 + r;
            int t = lT[row];
#pragma unroll
            for (int fn = 0; fn < 2; fn++) {
                int col = wn + fn * 16 + lm;
                float val = acc[fm][fn][r];
                if (isf32) atomicAdd((float*)out_ + (size_t)t * D_DIM + n0 + col, val);
                else       atomAddBf16((unsigned short*)out_ + (size_t)t * D_DIM + n0 + col, val);
            }
        }
}

// ---------------------------------------------------------------------------
extern "C" void kernel_launch(void* const* d_in, const int* in_sizes, int n_in,
                              void* d_out, int out_size, void* d_ws, size_t ws_size,
                              hipStream_t stream)
{
    const void* x   = d_in[0];
    const void* rw  = d_in[1];
    const void* rb  = d_in[2];
    const void* rw1 = d_in[3];
    const void* rw3 = d_in[4];
    const void* rw2 = d_in[5];
    const void* sw1 = d_in[6];
    const void* sw3 = d_in[7];
    const void* sw2 = d_in[8];

    const int T = in_sizes[0] / D_DIM;          // 4096
    const int SLOT_MAX = 2 * T + NEXP * BM;     // 9216
    const int MAXSEGR  = SLOT_MAX / BM;         // 72
    const int MAXSEGH  = MAXSEGR + 2 * (T / BM);// 136

    char* p = (char*)d_ws;
    int*    flag     = (int*)p;
    int*    nsegR    = (int*)(p + 64);
    int*    nsegAll  = (int*)(p + 96);
    int*    fill     = (int*)(p + 128);         // 8 x 16 ints (64B padded)
    int2*   segdesc  = (int2*)(p + 1024);       // up to 136 segs
    size_t  o = 4096;
    int*    topkE    = (int*)(p + o);    o += (size_t)4 * T;
    float2* topkG    = (float2*)(p + o); o += (size_t)8 * T;
    int2*   slotof   = (int2*)(p + o);   o += (size_t)8 * T;
    int*    toklist  = (int*)(p + o);    o += (size_t)4 * SLOT_MAX;
    float*  slotgate = (float*)(p + o);  o += (size_t)4 * SLOT_MAX;
    o = (o + 255) & ~(size_t)255;
    // layout: w1t | AbufSh | AbufRt | w3t | xb   (w3t+xb reused as Or; w1t as w2t)
    unsigned short* w1t    = (unsigned short*)(p + o); o += (size_t)NP * H_DIM * D_DIM * 2;
    unsigned short* AbufSh = (unsigned short*)(p + o); o += (size_t)T * (2 * H_DIM) * 2;
    unsigned short* AbufRt = (unsigned short*)(p + o); o += (size_t)SLOT_MAX * H_DIM * 2;
    unsigned short* w3t    = (unsigned short*)(p + o); o += (size_t)NP * H_DIM * D_DIM * 2;
    unsigned short* xb     = (unsigned short*)(p + o);
    const size_t REQ = o + (size_t)T * D_DIM * 2;   // ~47.35 MB
    const int fast = (ws_size >= REQ) ? 1 : 0;
    unsigned short* w2t = w1t;   // overlay: w1t dead after h_all
    unsigned short* Or  = w3t;   // overlay: w3t+xb (18.87MB) dead after h_all

    detect_kernel<<<1, 256, 0, stream>>>((const unsigned short*)x, flag);
    transp13_kernel<<<dim3(D_DIM / 32, H_DIM / 64, 2 * NP), 256, 0, stream>>>(
        rw1, rw3, sw1, sw3, w1t, w3t, flag);
    router_kernel<<<T / 4, 256, 0, stream>>>(x, rw, rb, flag, topkE, topkG, xb, fast, T);
    segcnt_kernel<<<1, 256, 0, stream>>>(topkE, T, fill, segdesc, nsegR, nsegAll, toklist, slotgate);
    gather_kernel<<<(T + 255) / 256, 256, 0, stream>>>(topkE, topkG, fill, toklist, slotgate, slotof, T);
    moe_h_all_kernel<<<dim3(MAXSEGH, H_DIM / 64), 256, 0, stream>>>(
        x, xb, w1t, w3t, flag, fast, toklist, slotgate, segdesc, nsegAll, AbufSh, AbufRt);
    transp_kernel<<<dim3(H_DIM / 32, D_DIM / 64, NP), 256, 0, stream>>>(rw2, sw2, w2t, H_DIM, D_DIM, flag);
    if (fast) {
        moe_out_routed_or_kernel<<<dim3(MAXSEGR, D_DIM / 64), 256, 0, stream>>>(
            AbufRt, w2t, segdesc, nsegR, Or);
        moe_out_shared_kernel<<<dim3(T / BM, D_DIM / 64), 256, 0, stream>>>(
            AbufSh, w2t, flag, 1, Or, slotof, d_out);
    } else {
        moe_out_shared_kernel<<<dim3(T / BM, D_DIM / 64), 256, 0, stream>>>(
            AbufSh, w2t, flag, 0, nullptr, nullptr, d_out);
        moe_out_routed_atomic_kernel<<<dim3(MAXSEGR, D_DIM / 64), 256, 0, stream>>>(
            AbufRt, w2t, segdesc, nsegR, toklist, flag, d_out);
    }
}

// Round 10
// 269.216 us; speedup vs baseline: 1.2669x; 1.0149x over previous
//
#include <hip/hip_runtime.h>
#include <stdint.h>

#define D_DIM 1024
#define H_DIM 512
#define NEXP  8
#define NP    10            // 8 routed + 2 shared expert passes

#define BM 128
#define BK 64
#define LDK 72              // padded stride (fallback atomic kernel only)

typedef __attribute__((ext_vector_type(8))) short short8;     // 8 bf16 MFMA operand
typedef __attribute__((ext_vector_type(4))) float floatx4;    // MFMA accumulator
typedef __attribute__((ext_vector_type(4))) unsigned int uint4v;
typedef __attribute__((ext_vector_type(4))) float float4v;

typedef __attribute__((address_space(3))) unsigned char* as3p;
typedef const __attribute__((address_space(1))) unsigned char* as1p;

__device__ __forceinline__ void async16(void* lds, const void* g) {
    // wave-uniform LDS base; HW scatters lane i -> lds + i*16
    __builtin_amdgcn_global_load_lds((as1p)g, (as3p)lds, 16, 0, 0);
}

__device__ __forceinline__ float bf2f(unsigned short u) {
    union { float f; unsigned int i; } v; v.i = ((unsigned int)u) << 16; return v.f;
}
__device__ __forceinline__ unsigned short f2bf(float f) {
    union { float f; unsigned int i; } v; v.f = f;
    unsigned int r = v.i + 0x7FFFu + ((v.i >> 16) & 1u);   // RNE
    return (unsigned short)(r >> 16);
}

// bf16 atomic add via CAS (fallback path only)
__device__ void atomAddBf16(unsigned short* pp, float v) {
    unsigned int* w = (unsigned int*)((size_t)pp & ~(size_t)3);
    const bool hi = ((size_t)pp & 2) != 0;
    unsigned int old = *w, assumed;
    do {
        assumed = old;
        unsigned short cur = hi ? (unsigned short)(assumed >> 16)
                                : (unsigned short)(assumed & 0xFFFFu);
        unsigned short nv = f2bf(bf2f(cur) + v);
        unsigned int repl = hi ? ((assumed & 0x0000FFFFu) | ((unsigned)nv << 16))
                               : ((assumed & 0xFFFF0000u) | nv);
        old = atomicCAS(w, assumed, repl);
    } while (old != assumed);
}

// ---------------------------------------------------------------------------
__global__ void detect_kernel(const unsigned short* __restrict__ x, int* flag)
{
    __shared__ int bad;
    if (threadIdx.x == 0) bad = 0;
    __syncthreads();
    int b = 0;
    for (int i = threadIdx.x; i < 8192; i += 256) {
        int e = (x[i] >> 7) & 0xFF;
        if (e >= 0xA0) b = 1;
    }
    if (b) atomicOr(&bad, 1);
    __syncthreads();
    if (threadIdx.x == 0) *flag = bad;
}

// ---------------------------------------------------------------------------
// w1 + w3 transpose+convert: z 0..9 -> w1t, z 10..19 -> w3t  ([K][N]->[N][K])
// ---------------------------------------------------------------------------
__global__ __launch_bounds__(256) void transp13_kernel(
    const void* __restrict__ rw1, const void* __restrict__ rw3,
    const void* __restrict__ sw1, const void* __restrict__ sw3,
    unsigned short* __restrict__ w1t, unsigned short* __restrict__ w3t,
    const int* __restrict__ flag)
{
    const int isf32 = *flag;
    const int z = blockIdx.z;
    const int grp = z / 10, zz = z % 10;
    const void* src_ = grp == 0 ? (zz < 8 ? rw1 : sw1) : (zz < 8 ? rw3 : sw3);
    unsigned short* dstB = grp == 0 ? w1t : w3t;
    const size_t moff = (size_t)(zz < 8 ? zz : zz - 8) * D_DIM * H_DIM;
    const int nl = threadIdx.x & 63, j = threadIdx.x >> 6;
    const int n = blockIdx.y * 64 + nl;
    const int k0 = blockIdx.x * 32 + j * 8;

    unsigned short v[8];
    if (isf32) {
        const float* src = (const float*)src_ + moff;
#pragma unroll
        for (int j2 = 0; j2 < 8; j2++) v[j2] = f2bf(src[(size_t)(k0 + j2) * H_DIM + n]);
    } else {
        const unsigned short* src = (const unsigned short*)src_ + moff;
#pragma unroll
        for (int j2 = 0; j2 < 8; j2++) v[j2] = src[(size_t)(k0 + j2) * H_DIM + n];
    }
    uint4v w;
#pragma unroll
    for (int q = 0; q < 4; q++) w[q] = (unsigned)v[2 * q] | ((unsigned)v[2 * q + 1] << 16);
    *(uint4v*)(dstB + ((size_t)zz * H_DIM + n) * D_DIM + k0) = w;
}

// ---------------------------------------------------------------------------
// Generic transpose (w2): src [nmat][K][N] -> dst bf16 [nmat][N][K]
// ---------------------------------------------------------------------------
__global__ __launch_bounds__(256) void transp_kernel(
    const void* __restrict__ rsrc, const void* __restrict__ ssrc,
    unsigned short* __restrict__ dst, int K, int N, const int* __restrict__ flag)
{
    const int isf32 = *flag;
    const int z = blockIdx.z;
    const size_t moff = (size_t)(z < 8 ? z : z - 8) * K * N;
    const int nl = threadIdx.x & 63, j = threadIdx.x >> 6;
    const int n = blockIdx.y * 64 + nl;
    const int k0 = blockIdx.x * 32 + j * 8;

    unsigned short v[8];
    if (isf32) {
        const float* src = (const float*)(z < 8 ? rsrc : ssrc) + moff;
#pragma unroll
        for (int j2 = 0; j2 < 8; j2++) v[j2] = f2bf(src[(size_t)(k0 + j2) * N + n]);
    } else {
        const unsigned short* src = (const unsigned short*)(z < 8 ? rsrc : ssrc) + moff;
#pragma unroll
        for (int j2 = 0; j2 < 8; j2++) v[j2] = src[(size_t)(k0 + j2) * N + n];
    }
    uint4v w;
#pragma unroll
    for (int q = 0; q < 4; q++) w[q] = (unsigned)v[2 * q] | ((unsigned)v[2 * q + 1] << 16);
    *(uint4v*)(dst + ((size_t)z * N + n) * K + k0) = w;
}

// ---------------------------------------------------------------------------
// Router: one wave per token -> top-2 ids + gates; fp32 mode also emits bf16 xb.
// ---------------------------------------------------------------------------
__global__ __launch_bounds__(256, 4) void router_kernel(
    const void* __restrict__ xv_, const void* __restrict__ rwv_,
    const void* __restrict__ rbv_, const int* __restrict__ flag,
    int* __restrict__ topkE, float2* __restrict__ topkG,
    unsigned short* __restrict__ xb, int useXb, int T)
{
    const int isf32 = *flag;
    int gid  = blockIdx.x * blockDim.x + threadIdx.x;
    int t    = gid >> 6;
    int lane = threadIdx.x & 63;
    if (t >= T) return;

    float acc[NEXP];
#pragma unroll
    for (int e = 0; e < NEXP; e++) acc[e] = 0.f;

    if (isf32) {
        const float* xr = (const float*)xv_ + (size_t)t * D_DIM;
        const float* rw = (const float*)rwv_;
        unsigned short* xo = xb + (size_t)t * D_DIM;
#pragma unroll 4
        for (int i = 0; i < D_DIM / 64; i++) {
            int d = i * 64 + lane;
            float xv = xr[d];
            if (useXb) xo[d] = f2bf(xv);
            float4v wa = *(const float4v*)(rw + (size_t)d * NEXP);
            float4v wb = *(const float4v*)(rw + (size_t)d * NEXP + 4);
#pragma unroll
            for (int q = 0; q < 4; q++) { acc[q] += xv * wa[q]; acc[q + 4] += xv * wb[q]; }
        }
    } else {
        const unsigned short* xr = (const unsigned short*)xv_ + (size_t)t * D_DIM;
        const unsigned short* rw = (const unsigned short*)rwv_;
#pragma unroll 4
        for (int i = 0; i < D_DIM / 64; i++) {
            int d = i * 64 + lane;
            float xv = bf2f(xr[d]);
            uint4v wv = *(const uint4v*)(rw + (size_t)d * NEXP);
#pragma unroll
            for (int q = 0; q < 4; q++) {
                unsigned int w = wv[q];
                acc[q * 2 + 0] += xv * bf2f((unsigned short)(w & 0xFFFFu));
                acc[q * 2 + 1] += xv * bf2f((unsigned short)(w >> 16));
            }
        }
    }
#pragma unroll
    for (int m = 32; m >= 1; m >>= 1) {
#pragma unroll
        for (int e = 0; e < NEXP; e++) acc[e] += __shfl_xor(acc[e], m, 64);
    }
    if (lane == 0) {
#pragma unroll
        for (int e = 0; e < NEXP; e++)
            acc[e] += isf32 ? ((const float*)rbv_)[e] : bf2f(((const unsigned short*)rbv_)[e]);
        int i1 = 0; float v1 = acc[0];
#pragma unroll
        for (int e = 1; e < NEXP; e++) if (acc[e] > v1) { v1 = acc[e]; i1 = e; }
        int i2 = -1; float v2 = -3.4e38f;
#pragma unroll
        for (int e = 0; e < NEXP; e++) if (e != i1 && acc[e] > v2) { v2 = acc[e]; i2 = e; }
        float g1 = 1.f / (1.f + __expf(v2 - v1));
        float g2 = 1.f - g1;
        topkE[t] = i1 | (i2 << 8);
        float2 g; g.x = g1; g.y = g2;
        topkG[t] = g;
    }
}

// ---------------------------------------------------------------------------
// segcnt: 256 threads, LDS-reduced histogram, padded routed segments + shared
// segments, pad-slot zeroing, 64B-padded fill bases.
// ---------------------------------------------------------------------------
__global__ __launch_bounds__(256) void segcnt_kernel(
    const int* __restrict__ topkE, int T,
    int* __restrict__ fill, int2* __restrict__ segdesc,
    int* __restrict__ nsegR, int* __restrict__ nsegAll,
    int* __restrict__ toklist, float* __restrict__ slotgate)
{
    __shared__ int hist[NEXP];
    const int tid = threadIdx.x;
    if (tid < NEXP) hist[tid] = 0;
    __syncthreads();
    int c[NEXP];
#pragma unroll
    for (int e = 0; e < NEXP; e++) c[e] = 0;
    for (int i = tid; i < T; i += 256) {
        int pk = topkE[i];
        int e0 = pk & 255, e1 = pk >> 8;
#pragma unroll
        for (int e = 0; e < NEXP; e++) c[e] += (e0 == e) + (e1 == e);
    }
#pragma unroll
    for (int m = 32; m >= 1; m >>= 1) {
#pragma unroll
        for (int e = 0; e < NEXP; e++) c[e] += __shfl_xor(c[e], m, 64);
    }
    if ((tid & 63) == 0) {
#pragma unroll
        for (int e = 0; e < NEXP; e++) atomicAdd(&hist[e], c[e]);
    }
    __syncthreads();
    int base[NEXP + 1];
    base[0] = 0;
#pragma unroll
    for (int e = 0; e < NEXP; e++) {
        int nsg = (hist[e] + BM - 1) / BM;
        base[e + 1] = base[e] + nsg * BM;
    }
    if (tid == 0) {
        int ns = 0;
        for (int e = 0; e < NEXP; e++)
            for (int b = base[e]; b < base[e + 1]; b += BM) {
                int2 s; s.x = e; s.y = b; segdesc[ns++] = s;
            }
        *nsegR = ns;
        for (int z = 0; z < 2; z++)
            for (int t0 = 0; t0 < T; t0 += BM) {
                int2 s; s.x = 8 + z; s.y = t0; segdesc[ns++] = s;
            }
        *nsegAll = ns;
    }
    if (tid < NEXP) fill[tid * 16] = base[tid];
    for (int e = 0; e < NEXP; e++)
        for (int i = base[e] + hist[e] + tid; i < base[e + 1]; i += 256) {
            toklist[i] = 0; slotgate[i] = 0.f;
        }
}

// ---------------------------------------------------------------------------
// gather: hierarchical slot assignment; records slotof per token.
// ---------------------------------------------------------------------------
__global__ __launch_bounds__(256) void gather_kernel(
    const int* __restrict__ topkE, const float2* __restrict__ topkG,
    int* __restrict__ fill, int* __restrict__ toklist,
    float* __restrict__ slotgate, int2* __restrict__ slotof, int T)
{
    __shared__ int hist[NEXP], sbase[NEXP], rank[NEXP];
    const int tid = threadIdx.x;
    if (tid < NEXP) { hist[tid] = 0; rank[tid] = 0; }
    __syncthreads();
    const int t = blockIdx.x * 256 + tid;
    int e0 = 0, e1 = 0; float2 g; g.x = 0.f; g.y = 0.f;
    const bool valid = (t < T);
    if (valid) {
        int pk = topkE[t]; g = topkG[t];
        e0 = pk & 255; e1 = pk >> 8;
        atomicAdd(&hist[e0], 1);
        atomicAdd(&hist[e1], 1);
    }
    __syncthreads();
    if (tid < NEXP) sbase[tid] = atomicAdd(&fill[tid * 16], hist[tid]);
    __syncthreads();
    if (valid) {
        int s0 = sbase[e0] + atomicAdd(&rank[e0], 1);
        int s1 = sbase[e1] + atomicAdd(&rank[e1], 1);
        toklist[s0] = t; slotgate[s0] = g.x;
        toklist[s1] = t; slotgate[s1] = g.y;
        int2 so; so.x = s0; so.y = s1;
        slotof[t] = so;
    }
}

// ---------------------------------------------------------------------------
// Unified hidden: 128x64 tile, dual acc, global_load_lds + XOR-swizzled LDS.
// XCD-locality grid: x = n0-tile (8), y = segment (MAXSEGH). id%8 = n0 -> each
// XCD holds a 2.6MB weight column slice resident in its L2.
// ---------------------------------------------------------------------------
__global__ __launch_bounds__(256, 4) void moe_h_all_kernel(
    const void* __restrict__ x_, const unsigned short* __restrict__ xb,
    const unsigned short* __restrict__ w1t, const unsigned short* __restrict__ w3t,
    const int* __restrict__ flag, int useXb,
    const int* __restrict__ toklist, const float* __restrict__ slotgate,
    const int2* __restrict__ segdesc, const int* __restrict__ nsegAll,
    unsigned short* __restrict__ AbufSh, unsigned short* __restrict__ AbufRt)
{
    __shared__ __align__(16) unsigned short lA[BM][64];
    __shared__ __align__(16) unsigned short lB1[64][64];
    __shared__ __align__(16) unsigned short lB3[64][64];
    __shared__ int   lT[BM];
    __shared__ float lG[BM];

    const int s = blockIdx.y;
    if (s >= *nsegAll) return;
    const int tid = threadIdx.x;
    const int2 sd = segdesc[s];
    const int e = sd.x, slot0 = sd.y;
    const int n0 = blockIdx.x * 64;
    const unsigned short* W1 = w1t + (size_t)e * H_DIM * D_DIM;
    const unsigned short* W3 = w3t + (size_t)e * H_DIM * D_DIM;

    if (tid < BM) {
        if (e < 8) { lT[tid] = toklist[slot0 + tid]; lG[tid] = slotgate[slot0 + tid]; }
        else       { lT[tid] = slot0 + tid;          lG[tid] = 1.f; }
    }
    __syncthreads();

    const int wave = tid >> 6, lane = tid & 63;
    const int wm = (wave >> 1) * 64, wn = (wave & 1) * 32;
    const int lm = lane & 15, lq = lane >> 4;
    const int sw = (lane & 7) ^ ((lane >> 3) & 7);   // source granule for my slot

    const int isf32 = *flag;
    const unsigned short* xs = (isf32 && useXb) ? xb : (const unsigned short*)x_;
    const bool conv = (isf32 && !useXb);

    const unsigned short* aSrc[4];
    const unsigned short* b1Src[2];
    const unsigned short* b3Src[2];
    if (!conv) {
#pragma unroll
        for (int j = 0; j < 4; j++) {
            int r = (4 * wave + j) * 8 + (lane >> 3);
            aSrc[j] = xs + (size_t)lT[r] * D_DIM + sw * 8;
        }
    }
#pragma unroll
    for (int j = 0; j < 2; j++) {
        int r = (2 * wave + j) * 8 + (lane >> 3);
        b1Src[j] = W1 + (size_t)(n0 + r) * D_DIM + sw * 8;
        b3Src[j] = W3 + (size_t)(n0 + r) * D_DIM + sw * 8;
    }
    unsigned short* lAf  = &lA[0][0];
    unsigned short* lB1f = &lB1[0][0];
    unsigned short* lB3f = &lB3[0][0];

    floatx4 acc1[4][2], acc3[4][2];
#pragma unroll
    for (int fm = 0; fm < 4; fm++)
#pragma unroll
        for (int fn = 0; fn < 2; fn++) {
            floatx4 zz = {0.f, 0.f, 0.f, 0.f};
            acc1[fm][fn] = zz; acc3[fm][fn] = zz;
        }

    for (int k0 = 0; k0 < D_DIM; k0 += BK) {
        if (!conv) {
#pragma unroll
            for (int j = 0; j < 4; j++)
                async16(lAf + (4 * wave + j) * 512, aSrc[j] + k0);
        } else {
            const float* xf = (const float*)x_;
#pragma unroll
            for (int i = 0; i < 4; i++) {
                int m = (tid >> 3) + i * 32, pos = (tid & 7);
                int gsrc = pos ^ (m & 7);
                const float* src = xf + (size_t)lT[m] * D_DIM + k0 + gsrc * 8;
                float4v a = *(const float4v*)src, b = *(const float4v*)(src + 4);
                uint4v v;
#pragma unroll
                for (int q = 0; q < 2; q++) {
                    v[q]     = (unsigned)f2bf(a[2 * q]) | ((unsigned)f2bf(a[2 * q + 1]) << 16);
                    v[q + 2] = (unsigned)f2bf(b[2 * q]) | ((unsigned)f2bf(b[2 * q + 1]) << 16);
                }
                *(uint4v*)&lA[m][pos * 8] = v;
            }
        }
#pragma unroll
        for (int j = 0; j < 2; j++) {
            async16(lB1f + (2 * wave + j) * 512, b1Src[j] + k0);
            async16(lB3f + (2 * wave + j) * 512, b3Src[j] + k0);
        }
        __syncthreads();
#pragma unroll
        for (int kk = 0; kk < BK; kk += 32) {
            const int p8 = (((kk >> 3) + lq) ^ (lm & 7)) * 8;
            short8 af[4], b1f[2], b3f[2];
#pragma unroll
            for (int fm = 0; fm < 4; fm++)
                af[fm] = *(const short8*)&lA[wm + fm * 16 + lm][p8];
#pragma unroll
            for (int fn = 0; fn < 2; fn++) {
                b1f[fn] = *(const short8*)&lB1[wn + fn * 16 + lm][p8];
                b3f[fn] = *(const short8*)&lB3[wn + fn * 16 + lm][p8];
            }
#pragma unroll
            for (int fm = 0; fm < 4; fm++)
#pragma unroll
                for (int fn = 0; fn < 2; fn++) {
                    acc1[fm][fn] = __builtin_amdgcn_mfma_f32_16x16x32_bf16(af[fm], b1f[fn], acc1[fm][fn], 0, 0, 0);
                    acc3[fm][fn] = __builtin_amdgcn_mfma_f32_16x16x32_bf16(af[fm], b3f[fn], acc3[fm][fn], 0, 0, 0);
                }
        }
        __syncthreads();
    }
#pragma unroll
    for (int fm = 0; fm < 4; fm++)
#pragma unroll
        for (int r = 0; r < 4; r++) {
            int row = wm + fm * 16 + lq * 4 + r;
            float g = lG[row];
#pragma unroll
            for (int fn = 0; fn < 2; fn++) {
                float a1 = acc1[fm][fn][r], a3 = acc3[fm][fn][r];
                float h = a1 / (1.f + __expf(-a1)) * a3 * g;
                int col = wn + fn * 16 + lm;
                if (e < 8)
                    AbufRt[(size_t)(slot0 + row) * H_DIM + n0 + col] = f2bf(h);
                else
                    AbufSh[(size_t)(slot0 + row) * (2 * H_DIM) + (e - 8) * H_DIM + n0 + col] = f2bf(h);
            }
        }
}

// ---------------------------------------------------------------------------
// Routed out: Or[slot,1024] = AbufRt[slot,512] @ w2_e. 128x64 tile.
// XCD-locality grid: x = n0-tile (16), y = segment (MAXSEGR).
// ---------------------------------------------------------------------------
__global__ __launch_bounds__(256, 4) void moe_out_routed_or_kernel(
    const unsigned short* __restrict__ Abuf, const unsigned short* __restrict__ w2t,
    const int2* __restrict__ segdesc, const int* __restrict__ nsegR,
    unsigned short* __restrict__ Or)
{
    __shared__ __align__(16) unsigned short lA[BM][64];
    __shared__ __align__(16) unsigned short lB[64][64];

    const int s = blockIdx.y;
    if (s >= *nsegR) return;
    const int tid = threadIdx.x;
    const int2 sd = segdesc[s];
    const int e = sd.x, slot0 = sd.y;
    const int n0 = blockIdx.x * 64;
    const unsigned short* W2 = w2t + (size_t)e * D_DIM * H_DIM;

    const int wave = tid >> 6, lane = tid & 63;
    const int wm = (wave >> 1) * 64, wn = (wave & 1) * 32;
    const int lm = lane & 15, lq = lane >> 4;
    const int sw = (lane & 7) ^ ((lane >> 3) & 7);

    const unsigned short* aSrc[4];
    const unsigned short* bSrc[2];
#pragma unroll
    for (int j = 0; j < 4; j++) {
        int r = (4 * wave + j) * 8 + (lane >> 3);
        aSrc[j] = Abuf + (size_t)(slot0 + r) * H_DIM + sw * 8;
    }
#pragma unroll
    for (int j = 0; j < 2; j++) {
        int r = (2 * wave + j) * 8 + (lane >> 3);
        bSrc[j] = W2 + (size_t)(n0 + r) * H_DIM + sw * 8;
    }
    unsigned short* lAf = &lA[0][0];
    unsigned short* lBf = &lB[0][0];

    floatx4 acc[4][2];
#pragma unroll
    for (int fm = 0; fm < 4; fm++)
#pragma unroll
        for (int fn = 0; fn < 2; fn++) { floatx4 zz = {0.f,0.f,0.f,0.f}; acc[fm][fn] = zz; }

    for (int k0 = 0; k0 < H_DIM; k0 += BK) {
#pragma unroll
        for (int j = 0; j < 4; j++)
            async16(lAf + (4 * wave + j) * 512, aSrc[j] + k0);
#pragma unroll
        for (int j = 0; j < 2; j++)
            async16(lBf + (2 * wave + j) * 512, bSrc[j] + k0);
        __syncthreads();
#pragma unroll
        for (int kk = 0; kk < BK; kk += 32) {
            const int p8 = (((kk >> 3) + lq) ^ (lm & 7)) * 8;
            short8 af[4], bf[2];
#pragma unroll
            for (int fm = 0; fm < 4; fm++) af[fm] = *(const short8*)&lA[wm + fm * 16 + lm][p8];
#pragma unroll
            for (int fn = 0; fn < 2; fn++) bf[fn] = *(const short8*)&lB[wn + fn * 16 + lm][p8];
#pragma unroll
            for (int fm = 0; fm < 4; fm++)
#pragma unroll
                for (int fn = 0; fn < 2; fn++)
                    acc[fm][fn] = __builtin_amdgcn_mfma_f32_16x16x32_bf16(af[fm], bf[fn], acc[fm][fn], 0, 0, 0);
        }
        __syncthreads();
    }
#pragma unroll
    for (int fm = 0; fm < 4; fm++)
#pragma unroll
        for (int r = 0; r < 4; r++) {
            int row = wm + fm * 16 + lq * 4 + r;
#pragma unroll
            for (int fn = 0; fn < 2; fn++) {
                int col = wn + fn * 16 + lm;
                Or[(size_t)(slot0 + row) * D_DIM + n0 + col] = f2bf(acc[fm][fn][r]);
            }
        }
}

// ---------------------------------------------------------------------------
// Shared out (+fused routed combine): out[t] = AbufSh[t]@sw2cat + Or[s0]+Or[s1]
// XCD-locality grid: x = n0-tile (16), y = t0-tile (T/128).
// ---------------------------------------------------------------------------
__global__ __launch_bounds__(256, 4) void moe_out_shared_kernel(
    const unsigned short* __restrict__ Abuf, const unsigned short* __restrict__ w2t,
    const int* __restrict__ flag, int fused,
    const unsigned short* __restrict__ Or, const int2* __restrict__ slotof,
    void* __restrict__ out_)
{
    __shared__ __align__(16) unsigned short lA[BM][64];
    __shared__ __align__(16) unsigned short lB[64][64];
    __shared__ int2 lS[BM];

    const int isf32 = *flag;
    const int tid = threadIdx.x;
    const int t0 = blockIdx.y * BM, n0 = blockIdx.x * 64;

    if (fused && tid < BM) lS[tid] = slotof[t0 + tid];
    __syncthreads();

    const int wave = tid >> 6, lane = tid & 63;
    const int wm = (wave >> 1) * 64, wn = (wave & 1) * 32;
    const int lm = lane & 15, lq = lane >> 4;
    const int sw = (lane & 7) ^ ((lane >> 3) & 7);

    const unsigned short* aSrc[4];
    size_t bRow[2];
#pragma unroll
    for (int j = 0; j < 4; j++) {
        int r = (4 * wave + j) * 8 + (lane >> 3);
        aSrc[j] = Abuf + (size_t)(t0 + r) * (2 * H_DIM) + sw * 8;
    }
#pragma unroll
    for (int j = 0; j < 2; j++) {
        int r = (2 * wave + j) * 8 + (lane >> 3);
        bRow[j] = (size_t)(n0 + r) * H_DIM + sw * 8;
    }
    unsigned short* lAf = &lA[0][0];
    unsigned short* lBf = &lB[0][0];

    floatx4 acc[4][2];
#pragma unroll
    for (int fm = 0; fm < 4; fm++)
#pragma unroll
        for (int fn = 0; fn < 2; fn++) { floatx4 zz = {0.f,0.f,0.f,0.f}; acc[fm][fn] = zz; }

    for (int k0 = 0; k0 < 2 * H_DIM; k0 += BK) {
        const unsigned short* W2 = w2t + (size_t)(8 + (k0 >> 9)) * D_DIM * H_DIM;
        const int kk0 = k0 & (H_DIM - 1);
#pragma unroll
        for (int j = 0; j < 4; j++)
            async16(lAf + (4 * wave + j) * 512, aSrc[j] + k0);
#pragma unroll
        for (int j = 0; j < 2; j++)
            async16(lBf + (2 * wave + j) * 512, W2 + bRow[j] + kk0);
        __syncthreads();
#pragma unroll
        for (int kk = 0; kk < BK; kk += 32) {
            const int p8 = (((kk >> 3) + lq) ^ (lm & 7)) * 8;
            short8 af[4], bf[2];
#pragma unroll
            for (int fm = 0; fm < 4; fm++) af[fm] = *(const short8*)&lA[wm + fm * 16 + lm][p8];
#pragma unroll
            for (int fn = 0; fn < 2; fn++) bf[fn] = *(const short8*)&lB[wn + fn * 16 + lm][p8];
#pragma unroll
            for (int fm = 0; fm < 4; fm++)
#pragma unroll
                for (int fn = 0; fn < 2; fn++)
                    acc[fm][fn] = __builtin_amdgcn_mfma_f32_16x16x32_bf16(af[fm], bf[fn], acc[fm][fn], 0, 0, 0);
        }
        __syncthreads();
    }
#pragma unroll
    for (int fm = 0; fm < 4; fm++)
#pragma unroll
        for (int r = 0; r < 4; r++) {
            int row = wm + fm * 16 + lq * 4 + r;
            int2 so; so.x = 0; so.y = 0;
            if (fused) so = lS[row];
#pragma unroll
            for (int fn = 0; fn < 2; fn++) {
                int col = wn + fn * 16 + lm;
                float val = acc[fm][fn][r];
                if (fused) {
                    val += bf2f(Or[(size_t)so.x * D_DIM + n0 + col]);
                    val += bf2f(Or[(size_t)so.y * D_DIM + n0 + col]);
                }
                size_t off = (size_t)(t0 + row) * D_DIM + n0 + col;
                if (isf32) ((float*)out_)[off] = val;
                else       ((unsigned short*)out_)[off] = f2bf(val);
            }
        }
}

// ---------------------------------------------------------------------------
// Routed out fallback (ws too small): atomic scatter, padded-LDS staging.
// ---------------------------------------------------------------------------
__global__ __launch_bounds__(256, 3) void moe_out_routed_atomic_kernel(
    const unsigned short* __restrict__ Abuf, const unsigned short* __restrict__ w2t,
    const int2* __restrict__ segdesc, const int* __restrict__ nsegR,
    const int* __restrict__ toklist, const int* __restrict__ flag,
    void* __restrict__ out_)
{
    __shared__ __align__(16) unsigned short lA[BM][LDK];
    __shared__ __align__(16) unsigned short lB[64][LDK];
    __shared__ int lT[BM];

    const int s = blockIdx.x;
    if (s >= *nsegR) return;
    const int isf32 = *flag;
    const int tid = threadIdx.x;
    const int2 sd = segdesc[s];
    const int e = sd.x, slot0 = sd.y;
    const int n0 = blockIdx.y * 64;
    const unsigned short* W2 = w2t + (size_t)e * D_DIM * H_DIM;

    if (tid < BM) lT[tid] = toklist[slot0 + tid];
    __syncthreads();

    floatx4 acc[4][2];
#pragma unroll
    for (int fm = 0; fm < 4; fm++)
#pragma unroll
        for (int fn = 0; fn < 2; fn++) { floatx4 zz = {0.f,0.f,0.f,0.f}; acc[fm][fn] = zz; }
    const int wave = tid >> 6, lane = tid & 63;
    const int wm = (wave >> 1) * 64, wn = (wave & 1) * 32;
    const int lm = lane & 15, lq = lane >> 4;

    for (int k0 = 0; k0 < H_DIM; k0 += BK) {
#pragma unroll
        for (int i = 0; i < 4; i++) {
            int m = (tid >> 3) + i * 32, kv = (tid & 7) * 8;
            *(uint4v*)&lA[m][kv] = *(const uint4v*)(Abuf + (size_t)(slot0 + m) * H_DIM + k0 + kv);
        }
#pragma unroll
        for (int i = 0; i < 2; i++) {
            int n = (tid >> 3) + i * 32, kc = (tid & 7) * 8;
            *(uint4v*)&lB[n][kc] = *(const uint4v*)(W2 + (size_t)(n0 + n) * H_DIM + k0 + kc);
        }
        __syncthreads();
#pragma unroll
        for (int kk = 0; kk < BK; kk += 32) {
            short8 af[4], bf[2];
#pragma unroll
            for (int fm = 0; fm < 4; fm++) af[fm] = *(const short8*)&lA[wm + fm * 16 + lm][kk + lq * 8];
#pragma unroll
            for (int fn = 0; fn < 2; fn++) bf[fn] = *(const short8*)&lB[wn + fn * 16 + lm][kk + lq * 8];
#pragma unroll
            for (int fm = 0; fm < 4; fm++)
#pragma unroll
                for (int fn = 0; fn < 2; fn++)
                    acc[fm][fn] = __builtin_amdgcn_mfma_f32_16x16x32_bf16(af[fm], bf[fn], acc[fm][fn], 0, 0, 0);
        }
        __syncthreads();
    }
#pragma unroll
    for (int fm = 0; fm < 4; fm++)
#pragma unroll
        for (int r = 0; r < 4; r++) {
            int row = wm + fm * 16 + lq * 4 + r;
            int t = lT[row];
#pragma unroll
            for (int fn = 0; fn < 2; fn++) {
                int col = wn + fn * 16 + lm;
                float val = acc[fm][fn][r];
                if (isf32) atomicAdd((float*)out_ + (size_t)t * D_DIM + n0 + col, val);
                else       atomAddBf16((unsigned short*)out_ + (size_t)t * D_DIM + n0 + col, val);
            }
        }
}

// ---------------------------------------------------------------------------
extern "C" void kernel_launch(void* const* d_in, const int* in_sizes, int n_in,
                              void* d_out, int out_size, void* d_ws, size_t ws_size,
                              hipStream_t stream)
{
    const void* x   = d_in[0];
    const void* rw  = d_in[1];
    const void* rb  = d_in[2];
    const void* rw1 = d_in[3];
    const void* rw3 = d_in[4];
    const void* rw2 = d_in[5];
    const void* sw1 = d_in[6];
    const void* sw3 = d_in[7];
    const void* sw2 = d_in[8];

    const int T = in_sizes[0] / D_DIM;          // 4096
    const int SLOT_MAX = 2 * T + NEXP * BM;     // 9216
    const int MAXSEGR  = SLOT_MAX / BM;         // 72
    const int MAXSEGH  = MAXSEGR + 2 * (T / BM);// 136

    char* p = (char*)d_ws;
    int*    flag     = (int*)p;
    int*    nsegR    = (int*)(p + 64);
    int*    nsegAll  = (int*)(p + 96);
    int*    fill     = (int*)(p + 128);         // 8 x 16 ints (64B padded)
    int2*   segdesc  = (int2*)(p + 1024);       // up to 136 segs
    size_t  o = 4096;
    int*    topkE    = (int*)(p + o);    o += (size_t)4 * T;
    float2* topkG    = (float2*)(p + o); o += (size_t)8 * T;
    int2*   slotof   = (int2*)(p + o);   o += (size_t)8 * T;
    int*    toklist  = (int*)(p + o);    o += (size_t)4 * SLOT_MAX;
    float*  slotgate = (float*)(p + o);  o += (size_t)4 * SLOT_MAX;
    o = (o + 255) & ~(size_t)255;
    // layout: w1t | AbufSh | AbufRt | w3t | xb | [w2sep]
    unsigned short* w1t    = (unsigned short*)(p + o); o += (size_t)NP * H_DIM * D_DIM * 2;
    unsigned short* AbufSh = (unsigned short*)(p + o); o += (size_t)T * (2 * H_DIM) * 2;
    unsigned short* AbufRt = (unsigned short*)(p + o); o += (size_t)SLOT_MAX * H_DIM * 2;
    unsigned short* w3t    = (unsigned short*)(p + o); o += (size_t)NP * H_DIM * D_DIM * 2;
    unsigned short* xb     = (unsigned short*)(p + o); o += (size_t)T * D_DIM * 2;
    const size_t REQ = o;                                   // ~47.35 MB
    unsigned short* w2sep  = (unsigned short*)(p + o); o += (size_t)NP * D_DIM * H_DIM * 2;
    const size_t REQ2 = o;                                  // ~57.84 MB
    const int fast  = (ws_size >= REQ)  ? 1 : 0;
    const int fast2 = (ws_size >= REQ2) ? 1 : 0;
    unsigned short* w2t = fast2 ? w2sep : w1t;  // overlay only if no room
    unsigned short* Or  = w3t;   // overlay: w3t+xb (18.87MB) dead after h_all

    detect_kernel<<<1, 256, 0, stream>>>((const unsigned short*)x, flag);
    transp13_kernel<<<dim3(D_DIM / 32, H_DIM / 64, 2 * NP), 256, 0, stream>>>(
        rw1, rw3, sw1, sw3, w1t, w3t, flag);
    if (fast2)   // w2 transpose early, removes mid-pipeline serialization
        transp_kernel<<<dim3(H_DIM / 32, D_DIM / 64, NP), 256, 0, stream>>>(
            rw2, sw2, w2t, H_DIM, D_DIM, flag);
    router_kernel<<<T / 4, 256, 0, stream>>>(x, rw, rb, flag, topkE, topkG, xb, fast, T);
    segcnt_kernel<<<1, 256, 0, stream>>>(topkE, T, fill, segdesc, nsegR, nsegAll, toklist, slotgate);
    gather_kernel<<<(T + 255) / 256, 256, 0, stream>>>(topkE, topkG, fill, toklist, slotgate, slotof, T);
    moe_h_all_kernel<<<dim3(H_DIM / 64, MAXSEGH), 256, 0, stream>>>(
        x, xb, w1t, w3t, flag, fast, toklist, slotgate, segdesc, nsegAll, AbufSh, AbufRt);
    if (!fast2)  // overlay path: must wait for h_all to free w1t
        transp_kernel<<<dim3(H_DIM / 32, D_DIM / 64, NP), 256, 0, stream>>>(
            rw2, sw2, w2t, H_DIM, D_DIM, flag);
    if (fast) {
        moe_out_routed_or_kernel<<<dim3(D_DIM / 64, MAXSEGR), 256, 0, stream>>>(
            AbufRt, w2t, segdesc, nsegR, Or);
        moe_out_shared_kernel<<<dim3(D_DIM / 64, T / BM), 256, 0, stream>>>(
            AbufSh, w2t, flag, 1, Or, slotof, d_out);
    } else {
        moe_out_shared_kernel<<<dim3(D_DIM / 64, T / BM), 256, 0, stream>>>(
            AbufSh, w2t, flag, 0, nullptr, nullptr, d_out);
        moe_out_routed_atomic_kernel<<<dim3(MAXSEGR, D_DIM / 64), 256, 0, stream>>>(
            AbufRt, w2t, segdesc, nsegR, toklist, flag, d_out);
    }
}